// Round 13
// baseline (815.853 us; speedup 1.0000x reference)
//
#include <hip/hip_runtime.h>
#include <hip/hip_bf16.h>
#include <stdint.h>

#define NN 10000
#define EE 50000
#define MPAD 50176  // EE padded to multiple of 128

typedef __hip_bfloat16 bf16_t;
typedef __attribute__((ext_vector_type(8))) short bf16x8;
typedef __attribute__((ext_vector_type(4))) float f32x4;

__device__ __forceinline__ float bf2f(unsigned short u) {
  union { unsigned int i; float f; } v; v.i = ((unsigned int)u) << 16; return v.f;
}

__device__ __forceinline__ void async_load16(const void* g, void* lds) {
  __builtin_amdgcn_global_load_lds((const __attribute__((address_space(1))) uint32_t*)g,
                                   (__attribute__((address_space(3))) uint32_t*)lds,
                                   16, 0, 0);
}

#define MFMA16(a, b, c) __builtin_amdgcn_mfma_f32_16x16x32_bf16(a, b, c, 0, 0, 0)

// C[M][N] = act(A[M][K] @ Bt[N][K]^T + bias[N]); bf16 row-major, M,N mult 128, K mult 64.
// Proven r2 structure: 944 TF, MfmaUtil 42%, 0 bank conflicts. DO NOT TOUCH without A/B.
template <bool RELU>
__global__ __launch_bounds__(256, 2)
void gemm_bt(const bf16_t* __restrict__ A, const bf16_t* __restrict__ Bt,
             const float* __restrict__ bias, bf16_t* __restrict__ C,
             int N, int K) {
  __shared__ __align__(16) bf16_t As[128 * 64];
  __shared__ __align__(16) bf16_t Bs[128 * 64];

  const int t = threadIdx.x;
  const int lane = t & 63;
  const int wave = t >> 6;
  const int nt = N >> 7;
  const int bm = blockIdx.x / nt;
  const int bn = blockIdx.x % nt;
  const size_t aRowBase = (size_t)bm << 7;
  const size_t bRowBase = (size_t)bn << 7;

  const int wrBase = (wave >> 1) << 6;
  const int wcBase = (wave & 1) << 6;
  const int lo = lane & 15;
  const int hi = lane >> 4;

  f32x4 acc[4][4] = {};

  const int stg_r = t >> 3;
  const int stg_s = t & 7;
  char* AsB = (char*)As;
  char* BsB = (char*)Bs;

  const int nkt = K >> 6;
  for (int kt = 0; kt < nkt; ++kt) {
    __syncthreads();
    #pragma unroll
    for (int it = 0; it < 4; ++it) {
      const int r = (it << 5) + stg_r;
      const int ls = (stg_s ^ (r & 7)) << 3;
      async_load16(A + (aRowBase + r) * K + (kt << 6) + ls,
                   AsB + (it << 12) + (wave << 10));
      async_load16(Bt + (bRowBase + r) * K + (kt << 6) + ls,
                   BsB + (it << 12) + (wave << 10));
    }
    __syncthreads();
    #pragma unroll
    for (int ks = 0; ks < 2; ++ks) {
      bf16x8 af[4], bfr[4];
      #pragma unroll
      for (int m = 0; m < 4; ++m) {
        const int row = wrBase + (m << 4) + lo;
        const int ps = ((ks << 2) + hi) ^ (row & 7);
        af[m] = *(const bf16x8*)(AsB + (row << 7) + (ps << 4));
      }
      #pragma unroll
      for (int n = 0; n < 4; ++n) {
        const int row = wcBase + (n << 4) + lo;
        const int ps = ((ks << 2) + hi) ^ (row & 7);
        bfr[n] = *(const bf16x8*)(BsB + (row << 7) + (ps << 4));
      }
      #pragma unroll
      for (int m = 0; m < 4; ++m)
        #pragma unroll
        for (int n = 0; n < 4; ++n)
          acc[m][n] = MFMA16(af[m], bfr[n], acc[m][n]);
    }
  }

  #pragma unroll
  for (int m = 0; m < 4; ++m) {
    #pragma unroll
    for (int n = 0; n < 4; ++n) {
      const int col = (bn << 7) + wcBase + (n << 4) + lo;
      const float bv = bias[col];
      #pragma unroll
      for (int j = 0; j < 4; ++j) {
        const int row = (bm << 7) + wrBase + (m << 4) + (hi << 2) + j;
        float v = acc[m][n][j] + bv;
        if (RELU) v = fmaxf(v, 0.0f);
        C[(size_t)row * N + col] = __float2bfloat16(v);
      }
    }
  }
}

// Merged per-layer dispatch (r12 structure, MOD generalized): fused tail blocks
// (bid%MOD==0) interleaved with cached-W msg blocks. Fused = r11 k3msgG body
// (s-major). Msg = msg_kernel body on Wcache edges [0, nMsgE).
__global__ __launch_bounds__(256, 2)
void layer_fused(const bf16_t* __restrict__ A, const bf16_t* __restrict__ Bt,
                 const float* __restrict__ b3, const float* __restrict__ h,
                 const bf16_t* __restrict__ Wc, const int* __restrict__ ei,
                 float* __restrict__ agg, int e0, int ne, int nmt, int nMsgE,
                 int MOD) {
  __shared__ __align__(16) char AsB[8192];    // [row64][slot8]*16B
  __shared__ __align__(16) char BsB[16384];   // [col128][slot8]*16B
  __shared__ __align__(16) float HL[64 * 20]; // h[row][s*16..+15], stride 20

  const int bid = blockIdx.x;
  const int t = threadIdx.x, lane = t & 63, w = t >> 6;

  if (bid % MOD != 0) {
    // ---- cached-W msg block (4 edges/block) ----
    const int mid = bid - bid / MOD - 1;
    const int el = (mid << 2) + (t >> 6);
    if (el >= nMsgE) return;
    const int g = lane >> 4, c = lane & 15;
    const unsigned src = (unsigned)ei[el], dst = (unsigned)ei[EE + el];
    if (src >= NN || dst >= NN) return;
    const float hv = h[src * 64 + lane];
    const unsigned short* We = (const unsigned short*)(Wc + (size_t)el * 4096);
    float a0 = 0, a1 = 0, a2 = 0, a3 = 0;
    #pragma unroll
    for (int i0 = 0; i0 < 64; i0 += 4) {
      const int i = i0 + g;
      const float hs = __shfl(hv, i);
      ushort4 wv = *(const ushort4*)(We + i * 64 + c * 4);
      a0 = fmaf(hs, bf2f(wv.x), a0);
      a1 = fmaf(hs, bf2f(wv.y), a1);
      a2 = fmaf(hs, bf2f(wv.z), a2);
      a3 = fmaf(hs, bf2f(wv.w), a3);
    }
    a0 += __shfl_xor(a0, 16); a0 += __shfl_xor(a0, 32);
    a1 += __shfl_xor(a1, 16); a1 += __shfl_xor(a1, 32);
    a2 += __shfl_xor(a2, 16); a2 += __shfl_xor(a2, 32);
    a3 += __shfl_xor(a3, 16); a3 += __shfl_xor(a3, 32);
    if (g == 0) {
      float* ag = agg + (size_t)dst * 64 + c * 4;
      atomicAdd(ag + 0, a0);
      atomicAdd(ag + 1, a1);
      atomicAdd(ag + 2, a2);
      atomicAdd(ag + 3, a3);
    }
    return;
  }

  // ---- fused k3-GEMM + msg tail block ----
  const int fid = bid / MOD;
  const int wrBase = (w >> 1) << 5;   // 0 or 32
  const int wcb = w & 1;              // col-half -> i parity
  const int wcBase = wcb << 6;        // 0 or 64
  const int lo = lane & 15, hi = lane >> 4;
  const int s = fid / nmt;            // s-major (Bt L2-resident per phase)
  const int mt = fid - s * nmt;
  const int aRow0 = mt << 6;

  {
    const int row = t >> 2, c4 = (t & 3) << 2;
    const int rg = aRow0 + row;
    float4 hv = make_float4(0.0f, 0.0f, 0.0f, 0.0f);
    if (rg < ne) {
      const unsigned sv = (unsigned)ei[e0 + rg];
      if (sv < NN) hv = *(const float4*)(h + ((size_t)sv << 6) + (s << 4) + c4);
    }
    *(float4*)(HL + row * 20 + c4) = hv;
  }

  const int str = t >> 3;  // 0..31
  const int sts = t & 7;

  float msg[2][4][4] = {};  // [mf][nf][j]

  for (int ct = 0; ct < 8; ++ct) {
    const int bn = (s << 3) + ct;
    f32x4 acc[2][4] = {};
    for (int kt = 0; kt < 8; ++kt) {
      __syncthreads();
      #pragma unroll
      for (int q = 0; q < 2; ++q) {
        const int r = str + (q << 5);
        const int ls = ((sts ^ (r & 7)) << 3);
        async_load16(A + (size_t)(aRow0 + r) * 512 + (kt << 6) + ls,
                     AsB + (q << 12) + (w << 10));
      }
      #pragma unroll
      for (int q = 0; q < 4; ++q) {
        const int c = str + (q << 5);
        const int ls = ((sts ^ (c & 7)) << 3);
        async_load16(Bt + (size_t)((bn << 7) + c) * 512 + (kt << 6) + ls,
                     BsB + (q << 12) + (w << 10));
      }
      __syncthreads();
      #pragma unroll
      for (int ks = 0; ks < 2; ++ks) {
        bf16x8 af[2], bfr[4];
        #pragma unroll
        for (int mf = 0; mf < 2; ++mf) {
          const int row = wrBase + (mf << 4) + lo;
          const int ps = ((ks << 2) + hi) ^ (row & 7);
          af[mf] = *(const bf16x8*)(AsB + (row << 7) + (ps << 4));
        }
        #pragma unroll
        for (int nf = 0; nf < 4; ++nf) {
          const int cl = wcBase + (nf << 4) + lo;
          const int ps = ((ks << 2) + hi) ^ (cl & 7);
          bfr[nf] = *(const bf16x8*)(BsB + (cl << 7) + (ps << 4));
        }
        #pragma unroll
        for (int mf = 0; mf < 2; ++mf)
          #pragma unroll
          for (int nf = 0; nf < 4; ++nf)
            acc[mf][nf] = MFMA16(af[mf], bfr[nf], acc[mf][nf]);
      }
    }
    const int iloc = (ct << 1) + wcb;
    float bv[4];
    #pragma unroll
    for (int nf = 0; nf < 4; ++nf)
      bv[nf] = b3[(bn << 7) + wcBase + (nf << 4) + lo];
    #pragma unroll
    for (int mf = 0; mf < 2; ++mf)
      #pragma unroll
      for (int j = 0; j < 4; ++j) {
        const int row = wrBase + (mf << 4) + (hi << 2) + j;
        const float hv = HL[row * 20 + iloc];
        #pragma unroll
        for (int nf = 0; nf < 4; ++nf)
          msg[mf][nf][j] = fmaf(hv, acc[mf][nf][j] + bv[nf], msg[mf][nf][j]);
      }
  }

  #pragma unroll
  for (int mf = 0; mf < 2; ++mf)
    #pragma unroll
    for (int j = 0; j < 4; ++j) {
      const int rg = aRow0 + wrBase + (mf << 4) + (hi << 2) + j;
      if (rg < ne) {
        const unsigned dst = (unsigned)ei[EE + e0 + rg];
        if (dst < NN) {
          float* ag = agg + ((size_t)dst << 6);
          #pragma unroll
          for (int nf = 0; nf < 4; ++nf)
            atomicAdd(ag + (nf << 4) + lo, msg[mf][nf][j]);
        }
      }
    }
}

// wt[n*K + k] = bf16(w[k*N + n])  (transpose + cast)
__global__ void convert_t(const float* __restrict__ w, bf16_t* __restrict__ wt,
                          int K, int N) {
  int idx = blockIdx.x * 256 + threadIdx.x;
  if (idx >= K * N) return;
  int n = idx / K, k = idx - n * K;
  wt[idx] = __float2bfloat16(w[(size_t)k * N + n]);
}

__global__ void fc1_kernel(const float* __restrict__ x, const float* __restrict__ w,
                           const float* __restrict__ b, float* __restrict__ h) {
  int idx = blockIdx.x * 256 + threadIdx.x;
  if (idx >= NN * 64) return;
  int n = idx >> 6, j = idx & 63;
  h[idx] = fmaf(x[n], w[j], b[j]);
}

__global__ void deg_kernel(const int* __restrict__ ei, float* __restrict__ deg) {
  int e = blockIdx.x * 256 + threadIdx.x;
  if (e < EE) {
    unsigned d = (unsigned)ei[EE + e];
    if (d < NN) atomicAdd(&deg[d], 1.0f);
  }
}

// e1[el][0:256] = relu(attr[e0+el] @ k1_w + k1_b), zeros for rows >= ne
__global__ void k1_kernel(const float* __restrict__ attr, const float* __restrict__ w,
                          const float* __restrict__ b, bf16_t* __restrict__ e1,
                          int e0, int ne) {
  const int el = blockIdx.x;
  const int j = threadIdx.x;
  __shared__ float a[6];
  if (el < ne && j < 6) a[j] = attr[(size_t)(e0 + el) * 6 + j];
  __syncthreads();
  float v = 0.0f;
  if (el < ne) {
    v = b[j];
    #pragma unroll
    for (int i = 0; i < 6; ++i) v = fmaf(a[i], w[i * 256 + j], v);
    v = fmaxf(v, 0.0f);
  }
  e1[(size_t)el * 256 + j] = __float2bfloat16(v);
}

// per-edge matvec from cached W (bf16): msg[o] = sum_i h[src][i]*W[el][i*64+o]
__global__ __launch_bounds__(256)
void msg_kernel(const float* __restrict__ h, const bf16_t* __restrict__ W,
                const int* __restrict__ ei, float* __restrict__ agg,
                int e0, int ne) {
  const int el = blockIdx.x * 4 + (threadIdx.x >> 6);
  if (el >= ne) return;
  const int e = e0 + el;
  const int lane = threadIdx.x & 63;
  const int g = lane >> 4, c = lane & 15;
  const unsigned src = (unsigned)ei[e], dst = (unsigned)ei[EE + e];
  if (src >= NN || dst >= NN) return;
  const float hv = h[src * 64 + lane];
  const unsigned short* We = (const unsigned short*)(W + (size_t)el * 4096);
  float a0 = 0, a1 = 0, a2 = 0, a3 = 0;
  #pragma unroll
  for (int i0 = 0; i0 < 64; i0 += 4) {
    const int i = i0 + g;
    const float hs = __shfl(hv, i);
    ushort4 wv = *(const ushort4*)(We + i * 64 + c * 4);
    a0 = fmaf(hs, bf2f(wv.x), a0);
    a1 = fmaf(hs, bf2f(wv.y), a1);
    a2 = fmaf(hs, bf2f(wv.z), a2);
    a3 = fmaf(hs, bf2f(wv.w), a3);
  }
  a0 += __shfl_xor(a0, 16); a0 += __shfl_xor(a0, 32);
  a1 += __shfl_xor(a1, 16); a1 += __shfl_xor(a1, 32);
  a2 += __shfl_xor(a2, 16); a2 += __shfl_xor(a2, 32);
  a3 += __shfl_xor(a3, 16); a3 += __shfl_xor(a3, 32);
  if (g == 0) {
    float* ag = agg + (size_t)dst * 64 + c * 4;
    atomicAdd(ag + 0, a0);
    atomicAdd(ag + 1, a1);
    atomicAdd(ag + 2, a2);
    atomicAdd(ag + 3, a3);
  }
}

// h_new = relu(agg/deg + h @ root + gcn_b)
__global__ __launch_bounds__(256)
void update_kernel(const float* __restrict__ h, const float* __restrict__ agg,
                   const float* __restrict__ deg, const float* __restrict__ root,
                   const float* __restrict__ gb, float* __restrict__ hn) {
  const int n = blockIdx.x * 4 + (threadIdx.x >> 6);
  if (n >= NN) return;
  const int lane = threadIdx.x & 63;
  const float hv = h[n * 64 + lane];
  float acc = 0.0f;
  #pragma unroll
  for (int i = 0; i < 64; ++i)
    acc = fmaf(__shfl(hv, i), root[i * 64 + lane], acc);
  const float d = fmaxf(deg[n], 1.0f);
  const float v = agg[n * 64 + lane] / d + acc + gb[lane];
  hn[n * 64 + lane] = fmaxf(v, 0.0f);
}

__global__ __launch_bounds__(256)
void fc2_kernel(const float* __restrict__ h, const float* __restrict__ w,
                const float* __restrict__ b, float* __restrict__ out) {
  const int n = blockIdx.x * 4 + (threadIdx.x >> 6);
  if (n >= NN) return;
  const int lane = threadIdx.x & 63;
  float v = h[n * 64 + lane] * w[lane];
  #pragma unroll
  for (int off = 32; off > 0; off >>= 1) v += __shfl_xor(v, off);
  if (lane == 0) out[n] = v + b[0];
}

extern "C" void kernel_launch(void* const* d_in, const int* in_sizes, int n_in,
                              void* d_out, int out_size, void* d_ws, size_t ws_size,
                              hipStream_t stream) {
  const float* x     = (const float*)d_in[0];
  const int*   ei    = (const int*)d_in[1];
  const float* attr  = (const float*)d_in[2];
  const float* fc1_w = (const float*)d_in[3];
  const float* fc1_b = (const float*)d_in[4];
  const float* k1_w  = (const float*)d_in[5];
  const float* k1_b  = (const float*)d_in[6];
  const float* k2_w  = (const float*)d_in[7];
  const float* k2_b  = (const float*)d_in[8];
  const float* k3_w  = (const float*)d_in[9];
  const float* k3_b  = (const float*)d_in[10];
  const float* root  = (const float*)d_in[11];
  const float* gcn_b = (const float*)d_in[12];
  const float* fc2_w = (const float*)d_in[13];
  const float* fc2_b = (const float*)d_in[14];
  float* out = (float*)d_out;
  (void)in_sizes; (void)n_in; (void)out_size;

  char* ws = (char*)d_ws;
  size_t off = 0;
  auto take = [&](size_t bytes) -> char* {
    char* p = ws + off;
    off += (bytes + 255) & ~(size_t)255;
    return p;
  };
  // fixed small buffers (~12.9 MB)
  bf16_t* k2wt = (bf16_t*)take((size_t)512 * 256 * 2);
  bf16_t* k3wt = (bf16_t*)take((size_t)4096 * 512 * 2);
  float*  hA   = (float*)take((size_t)NN * 64 * 4);
  float*  hB   = (float*)take((size_t)NN * 64 * 4);
  float*  agg  = (float*)take((size_t)NN * 64 * 4);
  float*  deg  = (float*)take((size_t)NN * 4);
  bf16_t* bounce = (bf16_t*)take((size_t)640 * 1024);  // cascade bounce: 640 e2 rows

  // Budget: Wcache Nc*8192 + e2tail TeP*1024 <= avail. Transients (e1 full 25.7MB,
  // e2cached Nc*1024) live INSIDE the Wcache region (dead before/at fill) via the
  // write-above-read fill cascade below.
  const size_t E1 = (size_t)MPAD * 512;  // e1 bytes (bf16 256/edge)
  size_t avail = (ws_size > off + 4096) ? ws_size - off - 4096 : 0;
  long ncl = ((long)avail - (long)EE * 1024 - 130048) / 7168;
  int Nc = (int)(ncl / 128) * 128;
  if (Nc > 49920) Nc = 49920;
  if (Nc < 8192) Nc = 0;  // cascade needs Nc >= 6784; below that, run all-fused
  const int Te = EE - Nc;
  const int TeP = (Te + 127) & ~127;

  bf16_t* e2tail = (bf16_t*)take((size_t)TeP * 1024);
  size_t wreg = (Nc > 0) ? (size_t)Nc * 8192 : E1;
  if (wreg < E1 + (size_t)Nc * 1024) wreg = E1 + (size_t)Nc * 1024;
  char* Wregion = take(wreg);
  bf16_t* Wcache = (bf16_t*)Wregion;                 // final: [Nc][4096] bf16
  bf16_t* e1    = (bf16_t*)Wregion;                  // transient: [MPAD][256] bf16
  bf16_t* e2c   = (bf16_t*)(Wregion + E1);           // transient: [Nc][512] bf16

  // weight transposes + casts
  convert_t<<<(512 * 256 + 255) / 256, 256, 0, stream>>>(k2_w, k2wt, 256, 512);
  convert_t<<<(4096 * 512 + 255) / 256, 256, 0, stream>>>(k3_w, k3wt, 512, 4096);

  // h0 = x @ fc1_w + fc1_b
  fc1_kernel<<<(NN * 64 + 255) / 256, 256, 0, stream>>>(x, fc1_w, fc1_b, hA);

  // in-degree
  hipMemsetAsync(deg, 0, NN * 4, stream);
  deg_kernel<<<(EE + 255) / 256, 256, 0, stream>>>(ei, deg);

  // k1 full -> e1 (in Wcache region)
  k1_kernel<<<MPAD, 256, 0, stream>>>(attr, k1_w, k1_b, e1, 0, EE);
  // k2: cached rows -> e2c (in Wcache region, above e1); tail rows -> e2tail
  if (Nc > 0)
    gemm_bt<true><<<(Nc >> 7) * 4, 256, 0, stream>>>(e1, k2wt, k2_b, e2c, 512, 256);
  gemm_bt<true><<<(TeP >> 7) * 4, 256, 0, stream>>>(e1 + (size_t)Nc * 256, k2wt, k2_b,
                                                    e2tail, 512, 256);

  // W cache fill cascade: write ranges provably above (or below) all concurrent reads.
  // Stage [r1,r2): reads e2c bytes [E1+r1*1024, E1+r2*1024), writes [r1*8192, r2*8192).
  if (Nc > 0) {
    // bounce rows [3072, 3712) of e2c (the cascade fixpoint gap)
    hipMemcpyAsync(bounce, (char*)e2c + (size_t)3072 * 1024, (size_t)640 * 1024,
                   hipMemcpyDeviceToDevice, stream);
    auto fill = [&](int r1, int r2, const bf16_t* Abase, int aRowOff) {
      if (r1 >= r2) return;
      gemm_bt<false><<<((r2 - r1) >> 7) * 32, 256, 0, stream>>>(
          Abase + (size_t)aRowOff * 512, k3wt, k3_b,
          Wcache + (size_t)r1 * 4096, 4096, 512);
    };
    fill(6784, Nc, e2c, 6784);      // writes >= 55.57M >= E1+Nc*1024 (Nc<=29180)
    fill(4096, 6784, e2c, 4096);    // writes >= 33.55M >= E1+6784*1024=32.64M
    fill(3712, 4096, e2c, 3712);    // writes >= 30.41M >= E1+4096*1024=29.88M
    fill(0, 3072, e2c, 0);          // writes <  25.17M <= E1 (all reads above E1)
    fill(3072, 3712, bounce, 0);    // reads bounce only; runs last
  }

  // merged-layer geometry
  const int Mt64 = (Te + 63) & ~63;
  const int nmt = Mt64 >> 6;
  const int nFused = nmt * 4;
  int ratio = 1, MOD = 1, NcIn = 0;
  if (Nc > 0 && nFused > 0) {
    ratio = (((Nc + 3) >> 2) + nFused - 1) / nFused;
    if (ratio < 1) ratio = 1;
    MOD = ratio + 1;
    const long cap = (long)4 * ratio * nFused;
    NcIn = (Nc < cap) ? Nc : (int)cap;
  }
  const int NcOut = Nc - NcIn;

  float* hc = hA;
  float* hn = hB;
  for (int l = 0; l < 3; ++l) {
    hipMemsetAsync(agg, 0, (size_t)NN * 64 * 4, stream);
    if (Te > 0) {
      layer_fused<<<nFused * MOD, 256, 0, stream>>>(e2tail, k3wt, k3_b, hc, Wcache,
                                                    ei, agg, Nc, Te, nmt, NcIn, MOD);
      if (NcOut > 0)
        msg_kernel<<<(NcOut + 3) / 4, 256, 0, stream>>>(hc, Wcache, ei, agg, NcIn, NcOut);
    } else if (Nc > 0) {
      msg_kernel<<<(Nc + 3) / 4, 256, 0, stream>>>(hc, Wcache, ei, agg, 0, Nc);
    }
    update_kernel<<<(NN + 3) / 4, 256, 0, stream>>>(hc, agg, deg, root, gcn_b, hn);
    float* tmp = hc; hc = hn; hn = tmp;
  }

  fc2_kernel<<<(NN + 3) / 4, 256, 0, stream>>>(hc, fc2_w, fc2_b, out);
}

// Round 14
// 786.783 us; speedup vs baseline: 1.0369x; 1.0369x over previous
//
#include <hip/hip_runtime.h>
#include <hip/hip_bf16.h>
#include <stdint.h>

#define NN 10000
#define EE 50000
#define MPAD 50176  // EE padded to multiple of 128

typedef __hip_bfloat16 bf16_t;
typedef __attribute__((ext_vector_type(8))) short bf16x8;
typedef __attribute__((ext_vector_type(4))) float f32x4;

__device__ __forceinline__ float bf2f(unsigned short u) {
  union { unsigned int i; float f; } v; v.i = ((unsigned int)u) << 16; return v.f;
}

__device__ __forceinline__ void async_load16(const void* g, void* lds) {
  __builtin_amdgcn_global_load_lds((const __attribute__((address_space(1))) uint32_t*)g,
                                   (__attribute__((address_space(3))) uint32_t*)lds,
                                   16, 0, 0);
}

#define MFMA16(a, b, c) __builtin_amdgcn_mfma_f32_16x16x32_bf16(a, b, c, 0, 0, 0)

// C[M][N] = act(A[M][K] @ Bt[N][K]^T + bias[N]); bf16 row-major, M,N mult 128, K mult 64.
// Proven r2 structure: 944 TF, MfmaUtil 42%, 0 bank conflicts. DO NOT TOUCH without A/B.
template <bool RELU>
__global__ __launch_bounds__(256, 2)
void gemm_bt(const bf16_t* __restrict__ A, const bf16_t* __restrict__ Bt,
             const float* __restrict__ bias, bf16_t* __restrict__ C,
             int N, int K) {
  __shared__ __align__(16) bf16_t As[128 * 64];
  __shared__ __align__(16) bf16_t Bs[128 * 64];

  const int t = threadIdx.x;
  const int lane = t & 63;
  const int wave = t >> 6;
  const int nt = N >> 7;
  const int bm = blockIdx.x / nt;
  const int bn = blockIdx.x % nt;
  const size_t aRowBase = (size_t)bm << 7;
  const size_t bRowBase = (size_t)bn << 7;

  const int wrBase = (wave >> 1) << 6;
  const int wcBase = (wave & 1) << 6;
  const int lo = lane & 15;
  const int hi = lane >> 4;

  f32x4 acc[4][4] = {};

  const int stg_r = t >> 3;
  const int stg_s = t & 7;
  char* AsB = (char*)As;
  char* BsB = (char*)Bs;

  const int nkt = K >> 6;
  for (int kt = 0; kt < nkt; ++kt) {
    __syncthreads();
    #pragma unroll
    for (int it = 0; it < 4; ++it) {
      const int r = (it << 5) + stg_r;
      const int ls = (stg_s ^ (r & 7)) << 3;
      async_load16(A + (aRowBase + r) * K + (kt << 6) + ls,
                   AsB + (it << 12) + (wave << 10));
      async_load16(Bt + (bRowBase + r) * K + (kt << 6) + ls,
                   BsB + (it << 12) + (wave << 10));
    }
    __syncthreads();
    #pragma unroll
    for (int ks = 0; ks < 2; ++ks) {
      bf16x8 af[4], bfr[4];
      #pragma unroll
      for (int m = 0; m < 4; ++m) {
        const int row = wrBase + (m << 4) + lo;
        const int ps = ((ks << 2) + hi) ^ (row & 7);
        af[m] = *(const bf16x8*)(AsB + (row << 7) + (ps << 4));
      }
      #pragma unroll
      for (int n = 0; n < 4; ++n) {
        const int row = wcBase + (n << 4) + lo;
        const int ps = ((ks << 2) + hi) ^ (row & 7);
        bfr[n] = *(const bf16x8*)(BsB + (row << 7) + (ps << 4));
      }
      #pragma unroll
      for (int m = 0; m < 4; ++m)
        #pragma unroll
        for (int n = 0; n < 4; ++n)
          acc[m][n] = MFMA16(af[m], bfr[n], acc[m][n]);
    }
  }

  #pragma unroll
  for (int m = 0; m < 4; ++m) {
    #pragma unroll
    for (int n = 0; n < 4; ++n) {
      const int col = (bn << 7) + wcBase + (n << 4) + lo;
      const float bv = bias[col];
      #pragma unroll
      for (int j = 0; j < 4; ++j) {
        const int row = (bm << 7) + wrBase + (m << 4) + (hi << 2) + j;
        float v = acc[m][n][j] + bv;
        if (RELU) v = fmaxf(v, 0.0f);
        C[(size_t)row * N + col] = __float2bfloat16(v);
      }
    }
  }
}

// Merged per-layer dispatch (r12 structure): fused tail blocks (bid%MOD==0)
// interleaved with cached-W msg blocks. Fused = r11 k3msgG body (s-major).
// Msg blocks: 8 edges/block, 2 per wave INTERLEAVED (two independent W streams
// per wave -> 2x memory-level parallelism; halves msg block count vs r12).
__global__ __launch_bounds__(256, 2)
void layer_fused(const bf16_t* __restrict__ A, const bf16_t* __restrict__ Bt,
                 const float* __restrict__ b3, const float* __restrict__ h,
                 const bf16_t* __restrict__ Wc, const int* __restrict__ ei,
                 float* __restrict__ agg, int e0, int ne, int nmt, int nMsgE,
                 int MOD) {
  __shared__ __align__(16) char AsB[8192];    // [row64][slot8]*16B
  __shared__ __align__(16) char BsB[16384];   // [col128][slot8]*16B
  __shared__ __align__(16) float HL[64 * 20]; // h[row][s*16..+15], stride 20

  const int bid = blockIdx.x;
  const int t = threadIdx.x, lane = t & 63, w = t >> 6;

  if (bid % MOD != 0) {
    // ---- cached-W msg block: 8 edges, 2 per wave, register-interleaved ----
    const int mid = bid - bid / MOD - 1;
    const int base = (mid << 3) + (t >> 6);
    const int el0 = base, el1 = base + 4;
    bool v0 = el0 < nMsgE, v1 = el1 < nMsgE;
    unsigned s0 = 0, d0 = 0, s1 = 0, d1 = 0;
    if (v0) { s0 = (unsigned)ei[el0]; d0 = (unsigned)ei[EE + el0];
              if (s0 >= NN || d0 >= NN) v0 = false; }
    if (v1) { s1 = (unsigned)ei[el1]; d1 = (unsigned)ei[EE + el1];
              if (s1 >= NN || d1 >= NN) v1 = false; }
    const int g = lane >> 4, c = lane & 15;
    const float hv0 = v0 ? h[s0 * 64 + lane] : 0.0f;
    const float hv1 = v1 ? h[s1 * 64 + lane] : 0.0f;
    const unsigned short* W0 =
        (const unsigned short*)(Wc + (size_t)(v0 ? el0 : 0) * 4096);
    const unsigned short* W1 =
        (const unsigned short*)(Wc + (size_t)(v1 ? el1 : 0) * 4096);
    float a0[4] = {}, a1[4] = {};
    #pragma unroll
    for (int i0 = 0; i0 < 64; i0 += 4) {
      const int i = i0 + g;
      const float hs0 = __shfl(hv0, i);
      const float hs1 = __shfl(hv1, i);
      ushort4 wv0 = *(const ushort4*)(W0 + i * 64 + c * 4);
      ushort4 wv1 = *(const ushort4*)(W1 + i * 64 + c * 4);
      a0[0] = fmaf(hs0, bf2f(wv0.x), a0[0]);
      a0[1] = fmaf(hs0, bf2f(wv0.y), a0[1]);
      a0[2] = fmaf(hs0, bf2f(wv0.z), a0[2]);
      a0[3] = fmaf(hs0, bf2f(wv0.w), a0[3]);
      a1[0] = fmaf(hs1, bf2f(wv1.x), a1[0]);
      a1[1] = fmaf(hs1, bf2f(wv1.y), a1[1]);
      a1[2] = fmaf(hs1, bf2f(wv1.z), a1[2]);
      a1[3] = fmaf(hs1, bf2f(wv1.w), a1[3]);
    }
    #pragma unroll
    for (int q = 0; q < 4; ++q) {
      a0[q] += __shfl_xor(a0[q], 16); a0[q] += __shfl_xor(a0[q], 32);
      a1[q] += __shfl_xor(a1[q], 16); a1[q] += __shfl_xor(a1[q], 32);
    }
    if (g == 0) {
      if (v0) {
        float* ag = agg + (size_t)d0 * 64 + c * 4;
        atomicAdd(ag + 0, a0[0]); atomicAdd(ag + 1, a0[1]);
        atomicAdd(ag + 2, a0[2]); atomicAdd(ag + 3, a0[3]);
      }
      if (v1) {
        float* ag = agg + (size_t)d1 * 64 + c * 4;
        atomicAdd(ag + 0, a1[0]); atomicAdd(ag + 1, a1[1]);
        atomicAdd(ag + 2, a1[2]); atomicAdd(ag + 3, a1[3]);
      }
    }
    return;
  }

  // ---- fused k3-GEMM + msg tail block (r11 k3msgG body) ----
  const int fid = bid / MOD;
  const int wrBase = (w >> 1) << 5;   // 0 or 32
  const int wcb = w & 1;              // col-half -> i parity
  const int wcBase = wcb << 6;        // 0 or 64
  const int lo = lane & 15, hi = lane >> 4;
  const int s = fid / nmt;            // s-major (Bt L2-resident per phase)
  const int mt = fid - s * nmt;
  const int aRow0 = mt << 6;

  {
    const int row = t >> 2, c4 = (t & 3) << 2;
    const int rg = aRow0 + row;
    float4 hv = make_float4(0.0f, 0.0f, 0.0f, 0.0f);
    if (rg < ne) {
      const unsigned sv = (unsigned)ei[e0 + rg];
      if (sv < NN) hv = *(const float4*)(h + ((size_t)sv << 6) + (s << 4) + c4);
    }
    *(float4*)(HL + row * 20 + c4) = hv;
  }

  const int str = t >> 3;  // 0..31
  const int sts = t & 7;

  float msg[2][4][4] = {};  // [mf][nf][j]

  for (int ct = 0; ct < 8; ++ct) {
    const int bn = (s << 3) + ct;
    f32x4 acc[2][4] = {};
    for (int kt = 0; kt < 8; ++kt) {
      __syncthreads();
      #pragma unroll
      for (int q = 0; q < 2; ++q) {
        const int r = str + (q << 5);
        const int ls = ((sts ^ (r & 7)) << 3);
        async_load16(A + (size_t)(aRow0 + r) * 512 + (kt << 6) + ls,
                     AsB + (q << 12) + (w << 10));
      }
      #pragma unroll
      for (int q = 0; q < 4; ++q) {
        const int c = str + (q << 5);
        const int ls = ((sts ^ (c & 7)) << 3);
        async_load16(Bt + (size_t)((bn << 7) + c) * 512 + (kt << 6) + ls,
                     BsB + (q << 12) + (w << 10));
      }
      __syncthreads();
      #pragma unroll
      for (int ks = 0; ks < 2; ++ks) {
        bf16x8 af[2], bfr[4];
        #pragma unroll
        for (int mf = 0; mf < 2; ++mf) {
          const int row = wrBase + (mf << 4) + lo;
          const int ps = ((ks << 2) + hi) ^ (row & 7);
          af[mf] = *(const bf16x8*)(AsB + (row << 7) + (ps << 4));
        }
        #pragma unroll
        for (int nf = 0; nf < 4; ++nf) {
          const int cl = wcBase + (nf << 4) + lo;
          const int ps = ((ks << 2) + hi) ^ (cl & 7);
          bfr[nf] = *(const bf16x8*)(BsB + (cl << 7) + (ps << 4));
        }
        #pragma unroll
        for (int mf = 0; mf < 2; ++mf)
          #pragma unroll
          for (int nf = 0; nf < 4; ++nf)
            acc[mf][nf] = MFMA16(af[mf], bfr[nf], acc[mf][nf]);
      }
    }
    const int iloc = (ct << 1) + wcb;
    float bv[4];
    #pragma unroll
    for (int nf = 0; nf < 4; ++nf)
      bv[nf] = b3[(bn << 7) + wcBase + (nf << 4) + lo];
    #pragma unroll
    for (int mf = 0; mf < 2; ++mf)
      #pragma unroll
      for (int j = 0; j < 4; ++j) {
        const int row = wrBase + (mf << 4) + (hi << 2) + j;
        const float hv = HL[row * 20 + iloc];
        #pragma unroll
        for (int nf = 0; nf < 4; ++nf)
          msg[mf][nf][j] = fmaf(hv, acc[mf][nf][j] + bv[nf], msg[mf][nf][j]);
      }
  }

  #pragma unroll
  for (int mf = 0; mf < 2; ++mf)
    #pragma unroll
    for (int j = 0; j < 4; ++j) {
      const int rg = aRow0 + wrBase + (mf << 4) + (hi << 2) + j;
      if (rg < ne) {
        const unsigned dst = (unsigned)ei[EE + e0 + rg];
        if (dst < NN) {
          float* ag = agg + ((size_t)dst << 6);
          #pragma unroll
          for (int nf = 0; nf < 4; ++nf)
            atomicAdd(ag + (nf << 4) + lo, msg[mf][nf][j]);
        }
      }
    }
}

// wt[n*K + k] = bf16(w[k*N + n])  (transpose + cast)
__global__ void convert_t(const float* __restrict__ w, bf16_t* __restrict__ wt,
                          int K, int N) {
  int idx = blockIdx.x * 256 + threadIdx.x;
  if (idx >= K * N) return;
  int n = idx / K, k = idx - n * K;
  wt[idx] = __float2bfloat16(w[(size_t)k * N + n]);
}

__global__ void fc1_kernel(const float* __restrict__ x, const float* __restrict__ w,
                           const float* __restrict__ b, float* __restrict__ h) {
  int idx = blockIdx.x * 256 + threadIdx.x;
  if (idx >= NN * 64) return;
  int n = idx >> 6, j = idx & 63;
  h[idx] = fmaf(x[n], w[j], b[j]);
}

__global__ void deg_kernel(const int* __restrict__ ei, float* __restrict__ deg) {
  int e = blockIdx.x * 256 + threadIdx.x;
  if (e < EE) {
    unsigned d = (unsigned)ei[EE + e];
    if (d < NN) atomicAdd(&deg[d], 1.0f);
  }
}

// e1[el][0:256] = relu(attr[e0+el] @ k1_w + k1_b), zeros for rows >= ne
__global__ void k1_kernel(const float* __restrict__ attr, const float* __restrict__ w,
                          const float* __restrict__ b, bf16_t* __restrict__ e1,
                          int e0, int ne) {
  const int el = blockIdx.x;
  const int j = threadIdx.x;
  __shared__ float a[6];
  if (el < ne && j < 6) a[j] = attr[(size_t)(e0 + el) * 6 + j];
  __syncthreads();
  float v = 0.0f;
  if (el < ne) {
    v = b[j];
    #pragma unroll
    for (int i = 0; i < 6; ++i) v = fmaf(a[i], w[i * 256 + j], v);
    v = fmaxf(v, 0.0f);
  }
  e1[(size_t)el * 256 + j] = __float2bfloat16(v);
}

// per-edge matvec from cached W (bf16): msg[o] = sum_i h[src][i]*W[el][i*64+o]
__global__ __launch_bounds__(256)
void msg_kernel(const float* __restrict__ h, const bf16_t* __restrict__ W,
                const int* __restrict__ ei, float* __restrict__ agg,
                int e0, int ne) {
  const int el = blockIdx.x * 4 + (threadIdx.x >> 6);
  if (el >= ne) return;
  const int e = e0 + el;
  const int lane = threadIdx.x & 63;
  const int g = lane >> 4, c = lane & 15;
  const unsigned src = (unsigned)ei[e], dst = (unsigned)ei[EE + e];
  if (src >= NN || dst >= NN) return;
  const float hv = h[src * 64 + lane];
  const unsigned short* We = (const unsigned short*)(W + (size_t)el * 4096);
  float a0 = 0, a1 = 0, a2 = 0, a3 = 0;
  #pragma unroll
  for (int i0 = 0; i0 < 64; i0 += 4) {
    const int i = i0 + g;
    const float hs = __shfl(hv, i);
    ushort4 wv = *(const ushort4*)(We + i * 64 + c * 4);
    a0 = fmaf(hs, bf2f(wv.x), a0);
    a1 = fmaf(hs, bf2f(wv.y), a1);
    a2 = fmaf(hs, bf2f(wv.z), a2);
    a3 = fmaf(hs, bf2f(wv.w), a3);
  }
  a0 += __shfl_xor(a0, 16); a0 += __shfl_xor(a0, 32);
  a1 += __shfl_xor(a1, 16); a1 += __shfl_xor(a1, 32);
  a2 += __shfl_xor(a2, 16); a2 += __shfl_xor(a2, 32);
  a3 += __shfl_xor(a3, 16); a3 += __shfl_xor(a3, 32);
  if (g == 0) {
    float* ag = agg + (size_t)dst * 64 + c * 4;
    atomicAdd(ag + 0, a0);
    atomicAdd(ag + 1, a1);
    atomicAdd(ag + 2, a2);
    atomicAdd(ag + 3, a3);
  }
}

// h_new = relu(agg/deg + h @ root + gcn_b)
__global__ __launch_bounds__(256)
void update_kernel(const float* __restrict__ h, const float* __restrict__ agg,
                   const float* __restrict__ deg, const float* __restrict__ root,
                   const float* __restrict__ gb, float* __restrict__ hn) {
  const int n = blockIdx.x * 4 + (threadIdx.x >> 6);
  if (n >= NN) return;
  const int lane = threadIdx.x & 63;
  const float hv = h[n * 64 + lane];
  float acc = 0.0f;
  #pragma unroll
  for (int i = 0; i < 64; ++i)
    acc = fmaf(__shfl(hv, i), root[i * 64 + lane], acc);
  const float d = fmaxf(deg[n], 1.0f);
  const float v = agg[n * 64 + lane] / d + acc + gb[lane];
  hn[n * 64 + lane] = fmaxf(v, 0.0f);
}

__global__ __launch_bounds__(256)
void fc2_kernel(const float* __restrict__ h, const float* __restrict__ w,
                const float* __restrict__ b, float* __restrict__ out) {
  const int n = blockIdx.x * 4 + (threadIdx.x >> 6);
  if (n >= NN) return;
  const int lane = threadIdx.x & 63;
  float v = h[n * 64 + lane] * w[lane];
  #pragma unroll
  for (int off = 32; off > 0; off >>= 1) v += __shfl_xor(v, off);
  if (lane == 0) out[n] = v + b[0];
}

extern "C" void kernel_launch(void* const* d_in, const int* in_sizes, int n_in,
                              void* d_out, int out_size, void* d_ws, size_t ws_size,
                              hipStream_t stream) {
  const float* x     = (const float*)d_in[0];
  const int*   ei    = (const int*)d_in[1];
  const float* attr  = (const float*)d_in[2];
  const float* fc1_w = (const float*)d_in[3];
  const float* fc1_b = (const float*)d_in[4];
  const float* k1_w  = (const float*)d_in[5];
  const float* k1_b  = (const float*)d_in[6];
  const float* k2_w  = (const float*)d_in[7];
  const float* k2_b  = (const float*)d_in[8];
  const float* k3_w  = (const float*)d_in[9];
  const float* k3_b  = (const float*)d_in[10];
  const float* root  = (const float*)d_in[11];
  const float* gcn_b = (const float*)d_in[12];
  const float* fc2_w = (const float*)d_in[13];
  const float* fc2_b = (const float*)d_in[14];
  float* out = (float*)d_out;
  (void)in_sizes; (void)n_in; (void)out_size;

  char* ws = (char*)d_ws;
  size_t off = 0;
  auto take = [&](size_t bytes) -> char* {
    char* p = ws + off;
    off += (bytes + 255) & ~(size_t)255;
    return p;
  };
  // fixed small buffers (~12.2 MB)
  bf16_t* k2wt = (bf16_t*)take((size_t)512 * 256 * 2);
  bf16_t* k3wt = (bf16_t*)take((size_t)4096 * 512 * 2);
  float*  hA   = (float*)take((size_t)NN * 64 * 4);
  float*  hB   = (float*)take((size_t)NN * 64 * 4);
  float*  agg  = (float*)take((size_t)NN * 64 * 4);
  float*  deg  = (float*)take((size_t)NN * 4);

  // e2 for all edges (51.4 MB); remaining region = e1 (transient) then Wcache
  bf16_t* e2full = (bf16_t*)take((size_t)MPAD * 512 * 2);
  size_t rem = (ws_size > off + 1024) ? ws_size - off - 1024 : 0;
  int Nc = (int)((rem / 8192) / 128) * 128;  // cached edges, mult of 128
  if (Nc > 49920) Nc = 49920;  // keep Te >= 80 (never let Te < 0)
  if (Nc < 0) Nc = 0;
  size_t e1B = (size_t)MPAD * 256 * 2;  // 25.7 MB
  size_t regionB = (size_t)Nc * 8192;
  if (regionB < e1B) regionB = e1B;
  char* region = take(regionB);
  bf16_t* Wcache = (bf16_t*)region;
  bf16_t* e1 = (bf16_t*)region;  // dead after k2; overwritten by Wcache fill

  const int Te = EE - Nc;               // tail edges (fused per layer)
  const int Mt64 = (Te + 63) & ~63;     // padded to 64 (Nc + Mt64 <= MPAD)
  const int nmt = Mt64 >> 6;
  const int nFused = nmt * 4;           // fused blocks (s-major: fid = s*nmt + mt)
  int ratio = 1, MOD = 1, NcIn = 0;
  if (Nc > 0 && nFused > 0) {
    // msg blocks now cover 8 edges each (2 per wave, interleaved)
    ratio = (((Nc + 7) >> 3) + nFused - 1) / nFused;
    if (ratio < 1) ratio = 1;
    MOD = ratio + 1;
    const long cap = (long)8 * ratio * nFused;
    NcIn = (Nc < cap) ? Nc : (int)cap;
  }
  const int NcOut = Nc - NcIn;

  // weight transposes + casts
  convert_t<<<(512 * 256 + 255) / 256, 256, 0, stream>>>(k2_w, k2wt, 256, 512);
  convert_t<<<(4096 * 512 + 255) / 256, 256, 0, stream>>>(k3_w, k3wt, 512, 4096);

  // h0 = x @ fc1_w + fc1_b
  fc1_kernel<<<(NN * 64 + 255) / 256, 256, 0, stream>>>(x, fc1_w, fc1_b, hA);

  // in-degree
  hipMemsetAsync(deg, 0, NN * 4, stream);
  deg_kernel<<<(EE + 255) / 256, 256, 0, stream>>>(ei, deg);

  // edge MLP front (full): k1 -> e1, k2 -> e2full
  k1_kernel<<<MPAD, 256, 0, stream>>>(attr, k1_w, k1_b, e1, 0, EE);
  gemm_bt<true><<<(MPAD >> 7) * 4, 256, 0, stream>>>(e1, k2wt, k2_b, e2full, 512, 256);

  // W cache fill (h-independent, once): proven 944-TF GEMM
  if (Nc > 0)
    gemm_bt<false><<<(Nc >> 7) * 32, 256, 0, stream>>>(e2full, k3wt, k3_b, Wcache, 4096, 512);

  float* hc = hA;
  float* hn = hB;
  for (int l = 0; l < 3; ++l) {
    hipMemsetAsync(agg, 0, (size_t)NN * 64 * 4, stream);
    if (Te > 0) {
      // merged dispatch: fused tail blocks (1/MOD) interleaved with cached-msg blocks
      layer_fused<<<nFused * MOD, 256, 0, stream>>>(e2full + (size_t)Nc * 512, k3wt, k3_b,
                                                    hc, Wcache, ei, agg, Nc, Te, nmt,
                                                    NcIn, MOD);
      if (NcOut > 0)
        msg_kernel<<<(NcOut + 7) / 4, 256, 0, stream>>>(hc, Wcache, ei, agg, NcIn, NcOut);
    } else if (Nc > 0) {
      msg_kernel<<<(Nc + 3) / 4, 256, 0, stream>>>(hc, Wcache, ei, agg, 0, Nc);
    }
    update_kernel<<<(NN + 3) / 4, 256, 0, stream>>>(hc, agg, deg, root, gcn_b, hn);
    float* tmp = hc; hc = hn; hn = tmp;
  }

  fc2_kernel<<<(NN + 3) / 4, 256, 0, stream>>>(hc, fc2_w, fc2_b, out);
}

// Round 15
// 778.914 us; speedup vs baseline: 1.0474x; 1.0101x over previous
//
#include <hip/hip_runtime.h>
#include <hip/hip_bf16.h>
#include <stdint.h>

#define NN 10000
#define EE 50000
#define MPAD 50176  // EE padded to multiple of 128

typedef __hip_bfloat16 bf16_t;
typedef __attribute__((ext_vector_type(8))) short bf16x8;
typedef __attribute__((ext_vector_type(4))) float f32x4;
typedef unsigned short u16x4 __attribute__((ext_vector_type(4)));

__device__ __forceinline__ float bf2f(unsigned short u) {
  union { unsigned int i; float f; } v; v.i = ((unsigned int)u) << 16; return v.f;
}

__device__ __forceinline__ void async_load16(const void* g, void* lds) {
  __builtin_amdgcn_global_load_lds((const __attribute__((address_space(1))) uint32_t*)g,
                                   (__attribute__((address_space(3))) uint32_t*)lds,
                                   16, 0, 0);
}

#define MFMA16(a, b, c) __builtin_amdgcn_mfma_f32_16x16x32_bf16(a, b, c, 0, 0, 0)

// C[M][N] = act(A[M][K] @ Bt[N][K]^T + bias[N]); bf16 row-major, M,N mult 128, K mult 64.
// Proven r2 structure: 944 TF, MfmaUtil 42%, 0 bank conflicts. DO NOT TOUCH without A/B.
template <bool RELU>
__global__ __launch_bounds__(256, 2)
void gemm_bt(const bf16_t* __restrict__ A, const bf16_t* __restrict__ Bt,
             const float* __restrict__ bias, bf16_t* __restrict__ C,
             int N, int K) {
  __shared__ __align__(16) bf16_t As[128 * 64];
  __shared__ __align__(16) bf16_t Bs[128 * 64];

  const int t = threadIdx.x;
  const int lane = t & 63;
  const int wave = t >> 6;
  const int nt = N >> 7;
  const int bm = blockIdx.x / nt;
  const int bn = blockIdx.x % nt;
  const size_t aRowBase = (size_t)bm << 7;
  const size_t bRowBase = (size_t)bn << 7;

  const int wrBase = (wave >> 1) << 6;
  const int wcBase = (wave & 1) << 6;
  const int lo = lane & 15;
  const int hi = lane >> 4;

  f32x4 acc[4][4] = {};

  const int stg_r = t >> 3;
  const int stg_s = t & 7;
  char* AsB = (char*)As;
  char* BsB = (char*)Bs;

  const int nkt = K >> 6;
  for (int kt = 0; kt < nkt; ++kt) {
    __syncthreads();
    #pragma unroll
    for (int it = 0; it < 4; ++it) {
      const int r = (it << 5) + stg_r;
      const int ls = (stg_s ^ (r & 7)) << 3;
      async_load16(A + (aRowBase + r) * K + (kt << 6) + ls,
                   AsB + (it << 12) + (wave << 10));
      async_load16(Bt + (bRowBase + r) * K + (kt << 6) + ls,
                   BsB + (it << 12) + (wave << 10));
    }
    __syncthreads();
    #pragma unroll
    for (int ks = 0; ks < 2; ++ks) {
      bf16x8 af[4], bfr[4];
      #pragma unroll
      for (int m = 0; m < 4; ++m) {
        const int row = wrBase + (m << 4) + lo;
        const int ps = ((ks << 2) + hi) ^ (row & 7);
        af[m] = *(const bf16x8*)(AsB + (row << 7) + (ps << 4));
      }
      #pragma unroll
      for (int n = 0; n < 4; ++n) {
        const int row = wcBase + (n << 4) + lo;
        const int ps = ((ks << 2) + hi) ^ (row & 7);
        bfr[n] = *(const bf16x8*)(BsB + (row << 7) + (ps << 4));
      }
      #pragma unroll
      for (int m = 0; m < 4; ++m)
        #pragma unroll
        for (int n = 0; n < 4; ++n)
          acc[m][n] = MFMA16(af[m], bfr[n], acc[m][n]);
    }
  }

  #pragma unroll
  for (int m = 0; m < 4; ++m) {
    #pragma unroll
    for (int n = 0; n < 4; ++n) {
      const int col = (bn << 7) + wcBase + (n << 4) + lo;
      const float bv = bias[col];
      #pragma unroll
      for (int j = 0; j < 4; ++j) {
        const int row = (bm << 7) + wrBase + (m << 4) + (hi << 2) + j;
        float v = acc[m][n][j] + bv;
        if (RELU) v = fmaxf(v, 0.0f);
        C[(size_t)row * N + col] = __float2bfloat16(v);
      }
    }
  }
}

// Merged per-layer dispatch (r14 structure): fused tail blocks (bid%MOD==0)
// interleaved with cached-W msg blocks (8 edges/block, 2 per wave interleaved).
// r15 delta: W-stream loads are NON-TEMPORAL (touched once/layer) so they stop
// evicting the L2-resident k3wt slices the s-major fused blocks depend on
// (r14 FETCH 331MB vs 255MB expected = ~76MB Bt re-fetch from msg pollution).
__global__ __launch_bounds__(256, 2)
void layer_fused(const bf16_t* __restrict__ A, const bf16_t* __restrict__ Bt,
                 const float* __restrict__ b3, const float* __restrict__ h,
                 const bf16_t* __restrict__ Wc, const int* __restrict__ ei,
                 float* __restrict__ agg, int e0, int ne, int nmt, int nMsgE,
                 int MOD) {
  __shared__ __align__(16) char AsB[8192];    // [row64][slot8]*16B
  __shared__ __align__(16) char BsB[16384];   // [col128][slot8]*16B
  __shared__ __align__(16) float HL[64 * 20]; // h[row][s*16..+15], stride 20

  const int bid = blockIdx.x;
  const int t = threadIdx.x, lane = t & 63, w = t >> 6;

  if (bid % MOD != 0) {
    // ---- cached-W msg block: 8 edges, 2 per wave, register-interleaved ----
    const int mid = bid - bid / MOD - 1;
    const int base = (mid << 3) + (t >> 6);
    const int el0 = base, el1 = base + 4;
    bool v0 = el0 < nMsgE, v1 = el1 < nMsgE;
    unsigned s0 = 0, d0 = 0, s1 = 0, d1 = 0;
    if (v0) { s0 = (unsigned)ei[el0]; d0 = (unsigned)ei[EE + el0];
              if (s0 >= NN || d0 >= NN) v0 = false; }
    if (v1) { s1 = (unsigned)ei[el1]; d1 = (unsigned)ei[EE + el1];
              if (s1 >= NN || d1 >= NN) v1 = false; }
    const int g = lane >> 4, c = lane & 15;
    const float hv0 = v0 ? h[s0 * 64 + lane] : 0.0f;
    const float hv1 = v1 ? h[s1 * 64 + lane] : 0.0f;
    const unsigned short* W0 =
        (const unsigned short*)(Wc + (size_t)(v0 ? el0 : 0) * 4096);
    const unsigned short* W1 =
        (const unsigned short*)(Wc + (size_t)(v1 ? el1 : 0) * 4096);
    float a0[4] = {}, a1[4] = {};
    #pragma unroll
    for (int i0 = 0; i0 < 64; i0 += 4) {
      const int i = i0 + g;
      const float hs0 = __shfl(hv0, i);
      const float hs1 = __shfl(hv1, i);
      u16x4 wv0 = __builtin_nontemporal_load((const u16x4*)(W0 + i * 64 + c * 4));
      u16x4 wv1 = __builtin_nontemporal_load((const u16x4*)(W1 + i * 64 + c * 4));
      a0[0] = fmaf(hs0, bf2f(wv0[0]), a0[0]);
      a0[1] = fmaf(hs0, bf2f(wv0[1]), a0[1]);
      a0[2] = fmaf(hs0, bf2f(wv0[2]), a0[2]);
      a0[3] = fmaf(hs0, bf2f(wv0[3]), a0[3]);
      a1[0] = fmaf(hs1, bf2f(wv1[0]), a1[0]);
      a1[1] = fmaf(hs1, bf2f(wv1[1]), a1[1]);
      a1[2] = fmaf(hs1, bf2f(wv1[2]), a1[2]);
      a1[3] = fmaf(hs1, bf2f(wv1[3]), a1[3]);
    }
    #pragma unroll
    for (int q = 0; q < 4; ++q) {
      a0[q] += __shfl_xor(a0[q], 16); a0[q] += __shfl_xor(a0[q], 32);
      a1[q] += __shfl_xor(a1[q], 16); a1[q] += __shfl_xor(a1[q], 32);
    }
    if (g == 0) {
      if (v0) {
        float* ag = agg + (size_t)d0 * 64 + c * 4;
        atomicAdd(ag + 0, a0[0]); atomicAdd(ag + 1, a0[1]);
        atomicAdd(ag + 2, a0[2]); atomicAdd(ag + 3, a0[3]);
      }
      if (v1) {
        float* ag = agg + (size_t)d1 * 64 + c * 4;
        atomicAdd(ag + 0, a1[0]); atomicAdd(ag + 1, a1[1]);
        atomicAdd(ag + 2, a1[2]); atomicAdd(ag + 3, a1[3]);
      }
    }
    return;
  }

  // ---- fused k3-GEMM + msg tail block (r11 k3msgG body) ----
  const int fid = bid / MOD;
  const int wrBase = (w >> 1) << 5;   // 0 or 32
  const int wcb = w & 1;              // col-half -> i parity
  const int wcBase = wcb << 6;        // 0 or 64
  const int lo = lane & 15, hi = lane >> 4;
  const int s = fid / nmt;            // s-major (Bt L2-resident per phase)
  const int mt = fid - s * nmt;
  const int aRow0 = mt << 6;

  {
    const int row = t >> 2, c4 = (t & 3) << 2;
    const int rg = aRow0 + row;
    float4 hv = make_float4(0.0f, 0.0f, 0.0f, 0.0f);
    if (rg < ne) {
      const unsigned sv = (unsigned)ei[e0 + rg];
      if (sv < NN) hv = *(const float4*)(h + ((size_t)sv << 6) + (s << 4) + c4);
    }
    *(float4*)(HL + row * 20 + c4) = hv;
  }

  const int str = t >> 3;  // 0..31
  const int sts = t & 7;

  float msg[2][4][4] = {};  // [mf][nf][j]

  for (int ct = 0; ct < 8; ++ct) {
    const int bn = (s << 3) + ct;
    f32x4 acc[2][4] = {};
    for (int kt = 0; kt < 8; ++kt) {
      __syncthreads();
      #pragma unroll
      for (int q = 0; q < 2; ++q) {
        const int r = str + (q << 5);
        const int ls = ((sts ^ (r & 7)) << 3);
        async_load16(A + (size_t)(aRow0 + r) * 512 + (kt << 6) + ls,
                     AsB + (q << 12) + (w << 10));
      }
      #pragma unroll
      for (int q = 0; q < 4; ++q) {
        const int c = str + (q << 5);
        const int ls = ((sts ^ (c & 7)) << 3);
        async_load16(Bt + (size_t)((bn << 7) + c) * 512 + (kt << 6) + ls,
                     BsB + (q << 12) + (w << 10));
      }
      __syncthreads();
      #pragma unroll
      for (int ks = 0; ks < 2; ++ks) {
        bf16x8 af[2], bfr[4];
        #pragma unroll
        for (int mf = 0; mf < 2; ++mf) {
          const int row = wrBase + (mf << 4) + lo;
          const int ps = ((ks << 2) + hi) ^ (row & 7);
          af[mf] = *(const bf16x8*)(AsB + (row << 7) + (ps << 4));
        }
        #pragma unroll
        for (int nf = 0; nf < 4; ++nf) {
          const int cl = wcBase + (nf << 4) + lo;
          const int ps = ((ks << 2) + hi) ^ (cl & 7);
          bfr[nf] = *(const bf16x8*)(BsB + (cl << 7) + (ps << 4));
        }
        #pragma unroll
        for (int mf = 0; mf < 2; ++mf)
          #pragma unroll
          for (int nf = 0; nf < 4; ++nf)
            acc[mf][nf] = MFMA16(af[mf], bfr[nf], acc[mf][nf]);
      }
    }
    const int iloc = (ct << 1) + wcb;
    float bv[4];
    #pragma unroll
    for (int nf = 0; nf < 4; ++nf)
      bv[nf] = b3[(bn << 7) + wcBase + (nf << 4) + lo];
    #pragma unroll
    for (int mf = 0; mf < 2; ++mf)
      #pragma unroll
      for (int j = 0; j < 4; ++j) {
        const int row = wrBase + (mf << 4) + (hi << 2) + j;
        const float hv = HL[row * 20 + iloc];
        #pragma unroll
        for (int nf = 0; nf < 4; ++nf)
          msg[mf][nf][j] = fmaf(hv, acc[mf][nf][j] + bv[nf], msg[mf][nf][j]);
      }
  }

  #pragma unroll
  for (int mf = 0; mf < 2; ++mf)
    #pragma unroll
    for (int j = 0; j < 4; ++j) {
      const int rg = aRow0 + wrBase + (mf << 4) + (hi << 2) + j;
      if (rg < ne) {
        const unsigned dst = (unsigned)ei[EE + e0 + rg];
        if (dst < NN) {
          float* ag = agg + ((size_t)dst << 6);
          #pragma unroll
          for (int nf = 0; nf < 4; ++nf)
            atomicAdd(ag + (nf << 4) + lo, msg[mf][nf][j]);
        }
      }
    }
}

// wt[n*K + k] = bf16(w[k*N + n])  (transpose + cast)
__global__ void convert_t(const float* __restrict__ w, bf16_t* __restrict__ wt,
                          int K, int N) {
  int idx = blockIdx.x * 256 + threadIdx.x;
  if (idx >= K * N) return;
  int n = idx / K, k = idx - n * K;
  wt[idx] = __float2bfloat16(w[(size_t)k * N + n]);
}

__global__ void fc1_kernel(const float* __restrict__ x, const float* __restrict__ w,
                           const float* __restrict__ b, float* __restrict__ h) {
  int idx = blockIdx.x * 256 + threadIdx.x;
  if (idx >= NN * 64) return;
  int n = idx >> 6, j = idx & 63;
  h[idx] = fmaf(x[n], w[j], b[j]);
}

__global__ void deg_kernel(const int* __restrict__ ei, float* __restrict__ deg) {
  int e = blockIdx.x * 256 + threadIdx.x;
  if (e < EE) {
    unsigned d = (unsigned)ei[EE + e];
    if (d < NN) atomicAdd(&deg[d], 1.0f);
  }
}

// e1[el][0:256] = relu(attr[e0+el] @ k1_w + k1_b), zeros for rows >= ne
__global__ void k1_kernel(const float* __restrict__ attr, const float* __restrict__ w,
                          const float* __restrict__ b, bf16_t* __restrict__ e1,
                          int e0, int ne) {
  const int el = blockIdx.x;
  const int j = threadIdx.x;
  __shared__ float a[6];
  if (el < ne && j < 6) a[j] = attr[(size_t)(e0 + el) * 6 + j];
  __syncthreads();
  float v = 0.0f;
  if (el < ne) {
    v = b[j];
    #pragma unroll
    for (int i = 0; i < 6; ++i) v = fmaf(a[i], w[i * 256 + j], v);
    v = fmaxf(v, 0.0f);
  }
  e1[(size_t)el * 256 + j] = __float2bfloat16(v);
}

// per-edge matvec from cached W (bf16): msg[o] = sum_i h[src][i]*W[el][i*64+o]
__global__ __launch_bounds__(256)
void msg_kernel(const float* __restrict__ h, const bf16_t* __restrict__ W,
                const int* __restrict__ ei, float* __restrict__ agg,
                int e0, int ne) {
  const int el = blockIdx.x * 4 + (threadIdx.x >> 6);
  if (el >= ne) return;
  const int e = e0 + el;
  const int lane = threadIdx.x & 63;
  const int g = lane >> 4, c = lane & 15;
  const unsigned src = (unsigned)ei[e], dst = (unsigned)ei[EE + e];
  if (src >= NN || dst >= NN) return;
  const float hv = h[src * 64 + lane];
  const unsigned short* We = (const unsigned short*)(W + (size_t)el * 4096);
  float a0 = 0, a1 = 0, a2 = 0, a3 = 0;
  #pragma unroll
  for (int i0 = 0; i0 < 64; i0 += 4) {
    const int i = i0 + g;
    const float hs = __shfl(hv, i);
    u16x4 wv = __builtin_nontemporal_load((const u16x4*)(We + i * 64 + c * 4));
    a0 = fmaf(hs, bf2f(wv[0]), a0);
    a1 = fmaf(hs, bf2f(wv[1]), a1);
    a2 = fmaf(hs, bf2f(wv[2]), a2);
    a3 = fmaf(hs, bf2f(wv[3]), a3);
  }
  a0 += __shfl_xor(a0, 16); a0 += __shfl_xor(a0, 32);
  a1 += __shfl_xor(a1, 16); a1 += __shfl_xor(a1, 32);
  a2 += __shfl_xor(a2, 16); a2 += __shfl_xor(a2, 32);
  a3 += __shfl_xor(a3, 16); a3 += __shfl_xor(a3, 32);
  if (g == 0) {
    float* ag = agg + (size_t)dst * 64 + c * 4;
    atomicAdd(ag + 0, a0);
    atomicAdd(ag + 1, a1);
    atomicAdd(ag + 2, a2);
    atomicAdd(ag + 3, a3);
  }
}

// h_new = relu(agg/deg + h @ root + gcn_b)
__global__ __launch_bounds__(256)
void update_kernel(const float* __restrict__ h, const float* __restrict__ agg,
                   const float* __restrict__ deg, const float* __restrict__ root,
                   const float* __restrict__ gb, float* __restrict__ hn) {
  const int n = blockIdx.x * 4 + (threadIdx.x >> 6);
  if (n >= NN) return;
  const int lane = threadIdx.x & 63;
  const float hv = h[n * 64 + lane];
  float acc = 0.0f;
  #pragma unroll
  for (int i = 0; i < 64; ++i)
    acc = fmaf(__shfl(hv, i), root[i * 64 + lane], acc);
  const float d = fmaxf(deg[n], 1.0f);
  const float v = agg[n * 64 + lane] / d + acc + gb[lane];
  hn[n * 64 + lane] = fmaxf(v, 0.0f);
}

__global__ __launch_bounds__(256)
void fc2_kernel(const float* __restrict__ h, const float* __restrict__ w,
                const float* __restrict__ b, float* __restrict__ out) {
  const int n = blockIdx.x * 4 + (threadIdx.x >> 6);
  if (n >= NN) return;
  const int lane = threadIdx.x & 63;
  float v = h[n * 64 + lane] * w[lane];
  #pragma unroll
  for (int off = 32; off > 0; off >>= 1) v += __shfl_xor(v, off);
  if (lane == 0) out[n] = v + b[0];
}

extern "C" void kernel_launch(void* const* d_in, const int* in_sizes, int n_in,
                              void* d_out, int out_size, void* d_ws, size_t ws_size,
                              hipStream_t stream) {
  const float* x     = (const float*)d_in[0];
  const int*   ei    = (const int*)d_in[1];
  const float* attr  = (const float*)d_in[2];
  const float* fc1_w = (const float*)d_in[3];
  const float* fc1_b = (const float*)d_in[4];
  const float* k1_w  = (const float*)d_in[5];
  const float* k1_b  = (const float*)d_in[6];
  const float* k2_w  = (const float*)d_in[7];
  const float* k2_b  = (const float*)d_in[8];
  const float* k3_w  = (const float*)d_in[9];
  const float* k3_b  = (const float*)d_in[10];
  const float* root  = (const float*)d_in[11];
  const float* gcn_b = (const float*)d_in[12];
  const float* fc2_w = (const float*)d_in[13];
  const float* fc2_b = (const float*)d_in[14];
  float* out = (float*)d_out;
  (void)in_sizes; (void)n_in; (void)out_size;

  char* ws = (char*)d_ws;
  size_t off = 0;
  auto take = [&](size_t bytes) -> char* {
    char* p = ws + off;
    off += (bytes + 255) & ~(size_t)255;
    return p;
  };
  // fixed small buffers (~12.2 MB)
  bf16_t* k2wt = (bf16_t*)take((size_t)512 * 256 * 2);
  bf16_t* k3wt = (bf16_t*)take((size_t)4096 * 512 * 2);
  float*  hA   = (float*)take((size_t)NN * 64 * 4);
  float*  hB   = (float*)take((size_t)NN * 64 * 4);
  float*  agg  = (float*)take((size_t)NN * 64 * 4);
  float*  deg  = (float*)take((size_t)NN * 4);

  // e2 for all edges (51.4 MB); remaining region = e1 (transient) then Wcache
  bf16_t* e2full = (bf16_t*)take((size_t)MPAD * 512 * 2);
  size_t rem = (ws_size > off + 1024) ? ws_size - off - 1024 : 0;
  int Nc = (int)((rem / 8192) / 128) * 128;  // cached edges, mult of 128
  if (Nc > 49920) Nc = 49920;  // keep Te >= 80 (never let Te < 0)
  if (Nc < 0) Nc = 0;
  size_t e1B = (size_t)MPAD * 256 * 2;  // 25.7 MB
  size_t regionB = (size_t)Nc * 8192;
  if (regionB < e1B) regionB = e1B;
  char* region = take(regionB);
  bf16_t* Wcache = (bf16_t*)region;
  bf16_t* e1 = (bf16_t*)region;  // dead after k2; overwritten by Wcache fill

  const int Te = EE - Nc;               // tail edges (fused per layer)
  const int Mt64 = (Te + 63) & ~63;     // padded to 64 (Nc + Mt64 <= MPAD)
  const int nmt = Mt64 >> 6;
  const int nFused = nmt * 4;           // fused blocks (s-major: fid = s*nmt + mt)
  int ratio = 1, MOD = 1, NcIn = 0;
  if (Nc > 0 && nFused > 0) {
    // msg blocks cover 8 edges each (2 per wave, interleaved)
    ratio = (((Nc + 7) >> 3) + nFused - 1) / nFused;
    if (ratio < 1) ratio = 1;
    MOD = ratio + 1;
    const long cap = (long)8 * ratio * nFused;
    NcIn = (Nc < cap) ? Nc : (int)cap;
  }
  const int NcOut = Nc - NcIn;

  // weight transposes + casts
  convert_t<<<(512 * 256 + 255) / 256, 256, 0, stream>>>(k2_w, k2wt, 256, 512);
  convert_t<<<(4096 * 512 + 255) / 256, 256, 0, stream>>>(k3_w, k3wt, 512, 4096);

  // h0 = x @ fc1_w + fc1_b
  fc1_kernel<<<(NN * 64 + 255) / 256, 256, 0, stream>>>(x, fc1_w, fc1_b, hA);

  // in-degree
  hipMemsetAsync(deg, 0, NN * 4, stream);
  deg_kernel<<<(EE + 255) / 256, 256, 0, stream>>>(ei, deg);

  // edge MLP front (full): k1 -> e1, k2 -> e2full
  k1_kernel<<<MPAD, 256, 0, stream>>>(attr, k1_w, k1_b, e1, 0, EE);
  gemm_bt<true><<<(MPAD >> 7) * 4, 256, 0, stream>>>(e1, k2wt, k2_b, e2full, 512, 256);

  // W cache fill (h-independent, once): proven 944-TF GEMM
  if (Nc > 0)
    gemm_bt<false><<<(Nc >> 7) * 32, 256, 0, stream>>>(e2full, k3wt, k3_b, Wcache, 4096, 512);

  float* hc = hA;
  float* hn = hB;
  for (int l = 0; l < 3; ++l) {
    hipMemsetAsync(agg, 0, (size_t)NN * 64 * 4, stream);
    if (Te > 0) {
      // merged dispatch: fused tail blocks (1/MOD) interleaved with cached-msg blocks
      layer_fused<<<nFused * MOD, 256, 0, stream>>>(e2full + (size_t)Nc * 512, k3wt, k3_b,
                                                    hc, Wcache, ei, agg, Nc, Te, nmt,
                                                    NcIn, MOD);
      if (NcOut > 0)
        msg_kernel<<<(NcOut + 3) / 4, 256, 0, stream>>>(hc, Wcache, ei, agg, NcIn, NcOut);
    } else if (Nc > 0) {
      msg_kernel<<<(Nc + 3) / 4, 256, 0, stream>>>(hc, Wcache, ei, agg, 0, Nc);
    }
    update_kernel<<<(NN + 3) / 4, 256, 0, stream>>>(hc, agg, deg, root, gcn_b, hn);
    float* tmp = hc; hc = hn; hn = tmp;
  }

  fc2_kernel<<<(NN + 3) / 4, 256, 0, stream>>>(hc, fc2_w, fc2_b, out);
}

// Round 16
// 753.445 us; speedup vs baseline: 1.0828x; 1.0338x over previous
//
#include <hip/hip_runtime.h>
#include <hip/hip_bf16.h>
#include <stdint.h>

#define NN 10000
#define EE 50000
#define MPAD 50176  // EE padded to multiple of 128

typedef __hip_bfloat16 bf16_t;
typedef __attribute__((ext_vector_type(8))) short bf16x8;
typedef __attribute__((ext_vector_type(4))) float f32x4;
typedef unsigned short u16x4 __attribute__((ext_vector_type(4)));

__device__ __forceinline__ float bf2f(unsigned short u) {
  union { unsigned int i; float f; } v; v.i = ((unsigned int)u) << 16; return v.f;
}

__device__ __forceinline__ void async_load16(const void* g, void* lds) {
  __builtin_amdgcn_global_load_lds((const __attribute__((address_space(1))) uint32_t*)g,
                                   (__attribute__((address_space(3))) uint32_t*)lds,
                                   16, 0, 0);
}

#define MFMA16(a, b, c) __builtin_amdgcn_mfma_f32_16x16x32_bf16(a, b, c, 0, 0, 0)

// C[M][N] = act(A[M][K] @ Bt[N][K]^T + bias[N]); bf16 row-major, M,N mult 128, K mult 64.
// Proven r2 structure: 944 TF, MfmaUtil 42%, 0 bank conflicts. DO NOT TOUCH without A/B.
template <bool RELU>
__global__ __launch_bounds__(256, 2)
void gemm_bt(const bf16_t* __restrict__ A, const bf16_t* __restrict__ Bt,
             const float* __restrict__ bias, bf16_t* __restrict__ C,
             int N, int K) {
  __shared__ __align__(16) bf16_t As[128 * 64];
  __shared__ __align__(16) bf16_t Bs[128 * 64];

  const int t = threadIdx.x;
  const int lane = t & 63;
  const int wave = t >> 6;
  const int nt = N >> 7;
  const int bm = blockIdx.x / nt;
  const int bn = blockIdx.x % nt;
  const size_t aRowBase = (size_t)bm << 7;
  const size_t bRowBase = (size_t)bn << 7;

  const int wrBase = (wave >> 1) << 6;
  const int wcBase = (wave & 1) << 6;
  const int lo = lane & 15;
  const int hi = lane >> 4;

  f32x4 acc[4][4] = {};

  const int stg_r = t >> 3;
  const int stg_s = t & 7;
  char* AsB = (char*)As;
  char* BsB = (char*)Bs;

  const int nkt = K >> 6;
  for (int kt = 0; kt < nkt; ++kt) {
    __syncthreads();
    #pragma unroll
    for (int it = 0; it < 4; ++it) {
      const int r = (it << 5) + stg_r;
      const int ls = (stg_s ^ (r & 7)) << 3;
      async_load16(A + (aRowBase + r) * K + (kt << 6) + ls,
                   AsB + (it << 12) + (wave << 10));
      async_load16(Bt + (bRowBase + r) * K + (kt << 6) + ls,
                   BsB + (it << 12) + (wave << 10));
    }
    __syncthreads();
    #pragma unroll
    for (int ks = 0; ks < 2; ++ks) {
      bf16x8 af[4], bfr[4];
      #pragma unroll
      for (int m = 0; m < 4; ++m) {
        const int row = wrBase + (m << 4) + lo;
        const int ps = ((ks << 2) + hi) ^ (row & 7);
        af[m] = *(const bf16x8*)(AsB + (row << 7) + (ps << 4));
      }
      #pragma unroll
      for (int n = 0; n < 4; ++n) {
        const int row = wcBase + (n << 4) + lo;
        const int ps = ((ks << 2) + hi) ^ (row & 7);
        bfr[n] = *(const bf16x8*)(BsB + (row << 7) + (ps << 4));
      }
      #pragma unroll
      for (int m = 0; m < 4; ++m)
        #pragma unroll
        for (int n = 0; n < 4; ++n)
          acc[m][n] = MFMA16(af[m], bfr[n], acc[m][n]);
    }
  }

  #pragma unroll
  for (int m = 0; m < 4; ++m) {
    #pragma unroll
    for (int n = 0; n < 4; ++n) {
      const int col = (bn << 7) + wcBase + (n << 4) + lo;
      const float bv = bias[col];
      #pragma unroll
      for (int j = 0; j < 4; ++j) {
        const int row = (bm << 7) + wrBase + (m << 4) + (hi << 2) + j;
        float v = acc[m][n][j] + bv;
        if (RELU) v = fmaxf(v, 0.0f);
        C[(size_t)row * N + col] = __float2bfloat16(v);
      }
    }
  }
}

// Merged per-layer dispatch (r15 structure): fused tail blocks (bid%MOD==0)
// interleaved with cached-W msg blocks (8 edges/block, 2/wave interleaved, NT loads).
// r16 delta: __launch_bounds__(256, 4) -- fused body uses 76 VGPR + 32 AGPR = 108
// unified regs <= 512/4 = 128 cap, so NO spill (r7's failure was cap 64 < 130 live);
// declares 4 waves/EU so up to 4 blocks/CU co-resident (vs measured 2.2 at (256,2)),
// doubling the wave pool that hides each fused block's stage->vmcnt drain (m114).
__global__ __launch_bounds__(256, 4)
void layer_fused(const bf16_t* __restrict__ A, const bf16_t* __restrict__ Bt,
                 const float* __restrict__ b3, const float* __restrict__ h,
                 const bf16_t* __restrict__ Wc, const int* __restrict__ ei,
                 float* __restrict__ agg, int e0, int ne, int nmt, int nMsgE,
                 int MOD) {
  __shared__ __align__(16) char AsB[8192];    // [row64][slot8]*16B
  __shared__ __align__(16) char BsB[16384];   // [col128][slot8]*16B
  __shared__ __align__(16) float HL[64 * 20]; // h[row][s*16..+15], stride 20

  const int bid = blockIdx.x;
  const int t = threadIdx.x, lane = t & 63, w = t >> 6;

  if (bid % MOD != 0) {
    // ---- cached-W msg block: 8 edges, 2 per wave, register-interleaved ----
    const int mid = bid - bid / MOD - 1;
    const int base = (mid << 3) + (t >> 6);
    const int el0 = base, el1 = base + 4;
    bool v0 = el0 < nMsgE, v1 = el1 < nMsgE;
    unsigned s0 = 0, d0 = 0, s1 = 0, d1 = 0;
    if (v0) { s0 = (unsigned)ei[el0]; d0 = (unsigned)ei[EE + el0];
              if (s0 >= NN || d0 >= NN) v0 = false; }
    if (v1) { s1 = (unsigned)ei[el1]; d1 = (unsigned)ei[EE + el1];
              if (s1 >= NN || d1 >= NN) v1 = false; }
    const int g = lane >> 4, c = lane & 15;
    const float hv0 = v0 ? h[s0 * 64 + lane] : 0.0f;
    const float hv1 = v1 ? h[s1 * 64 + lane] : 0.0f;
    const unsigned short* W0 =
        (const unsigned short*)(Wc + (size_t)(v0 ? el0 : 0) * 4096);
    const unsigned short* W1 =
        (const unsigned short*)(Wc + (size_t)(v1 ? el1 : 0) * 4096);
    float a0[4] = {}, a1[4] = {};
    #pragma unroll
    for (int i0 = 0; i0 < 64; i0 += 4) {
      const int i = i0 + g;
      const float hs0 = __shfl(hv0, i);
      const float hs1 = __shfl(hv1, i);
      u16x4 wv0 = __builtin_nontemporal_load((const u16x4*)(W0 + i * 64 + c * 4));
      u16x4 wv1 = __builtin_nontemporal_load((const u16x4*)(W1 + i * 64 + c * 4));
      a0[0] = fmaf(hs0, bf2f(wv0[0]), a0[0]);
      a0[1] = fmaf(hs0, bf2f(wv0[1]), a0[1]);
      a0[2] = fmaf(hs0, bf2f(wv0[2]), a0[2]);
      a0[3] = fmaf(hs0, bf2f(wv0[3]), a0[3]);
      a1[0] = fmaf(hs1, bf2f(wv1[0]), a1[0]);
      a1[1] = fmaf(hs1, bf2f(wv1[1]), a1[1]);
      a1[2] = fmaf(hs1, bf2f(wv1[2]), a1[2]);
      a1[3] = fmaf(hs1, bf2f(wv1[3]), a1[3]);
    }
    #pragma unroll
    for (int q = 0; q < 4; ++q) {
      a0[q] += __shfl_xor(a0[q], 16); a0[q] += __shfl_xor(a0[q], 32);
      a1[q] += __shfl_xor(a1[q], 16); a1[q] += __shfl_xor(a1[q], 32);
    }
    if (g == 0) {
      if (v0) {
        float* ag = agg + (size_t)d0 * 64 + c * 4;
        atomicAdd(ag + 0, a0[0]); atomicAdd(ag + 1, a0[1]);
        atomicAdd(ag + 2, a0[2]); atomicAdd(ag + 3, a0[3]);
      }
      if (v1) {
        float* ag = agg + (size_t)d1 * 64 + c * 4;
        atomicAdd(ag + 0, a1[0]); atomicAdd(ag + 1, a1[1]);
        atomicAdd(ag + 2, a1[2]); atomicAdd(ag + 3, a1[3]);
      }
    }
    return;
  }

  // ---- fused k3-GEMM + msg tail block (r11 k3msgG body) ----
  const int fid = bid / MOD;
  const int wrBase = (w >> 1) << 5;   // 0 or 32
  const int wcb = w & 1;              // col-half -> i parity
  const int wcBase = wcb << 6;        // 0 or 64
  const int lo = lane & 15, hi = lane >> 4;
  const int s = fid / nmt;            // s-major (Bt L2-resident per phase)
  const int mt = fid - s * nmt;
  const int aRow0 = mt << 6;

  {
    const int row = t >> 2, c4 = (t & 3) << 2;
    const int rg = aRow0 + row;
    float4 hv = make_float4(0.0f, 0.0f, 0.0f, 0.0f);
    if (rg < ne) {
      const unsigned sv = (unsigned)ei[e0 + rg];
      if (sv < NN) hv = *(const float4*)(h + ((size_t)sv << 6) + (s << 4) + c4);
    }
    *(float4*)(HL + row * 20 + c4) = hv;
  }

  const int str = t >> 3;  // 0..31
  const int sts = t & 7;

  float msg[2][4][4] = {};  // [mf][nf][j]

  for (int ct = 0; ct < 8; ++ct) {
    const int bn = (s << 3) + ct;
    f32x4 acc[2][4] = {};
    for (int kt = 0; kt < 8; ++kt) {
      __syncthreads();
      #pragma unroll
      for (int q = 0; q < 2; ++q) {
        const int r = str + (q << 5);
        const int ls = ((sts ^ (r & 7)) << 3);
        async_load16(A + (size_t)(aRow0 + r) * 512 + (kt << 6) + ls,
                     AsB + (q << 12) + (w << 10));
      }
      #pragma unroll
      for (int q = 0; q < 4; ++q) {
        const int c = str + (q << 5);
        const int ls = ((sts ^ (c & 7)) << 3);
        async_load16(Bt + (size_t)((bn << 7) + c) * 512 + (kt << 6) + ls,
                     BsB + (q << 12) + (w << 10));
      }
      __syncthreads();
      #pragma unroll
      for (int ks = 0; ks < 2; ++ks) {
        bf16x8 af[2], bfr[4];
        #pragma unroll
        for (int mf = 0; mf < 2; ++mf) {
          const int row = wrBase + (mf << 4) + lo;
          const int ps = ((ks << 2) + hi) ^ (row & 7);
          af[mf] = *(const bf16x8*)(AsB + (row << 7) + (ps << 4));
        }
        #pragma unroll
        for (int nf = 0; nf < 4; ++nf) {
          const int cl = wcBase + (nf << 4) + lo;
          const int ps = ((ks << 2) + hi) ^ (cl & 7);
          bfr[nf] = *(const bf16x8*)(BsB + (cl << 7) + (ps << 4));
        }
        #pragma unroll
        for (int mf = 0; mf < 2; ++mf)
          #pragma unroll
          for (int nf = 0; nf < 4; ++nf)
            acc[mf][nf] = MFMA16(af[mf], bfr[nf], acc[mf][nf]);
      }
    }
    const int iloc = (ct << 1) + wcb;
    float bv[4];
    #pragma unroll
    for (int nf = 0; nf < 4; ++nf)
      bv[nf] = b3[(bn << 7) + wcBase + (nf << 4) + lo];
    #pragma unroll
    for (int mf = 0; mf < 2; ++mf)
      #pragma unroll
      for (int j = 0; j < 4; ++j) {
        const int row = wrBase + (mf << 4) + (hi << 2) + j;
        const float hv = HL[row * 20 + iloc];
        #pragma unroll
        for (int nf = 0; nf < 4; ++nf)
          msg[mf][nf][j] = fmaf(hv, acc[mf][nf][j] + bv[nf], msg[mf][nf][j]);
      }
  }

  #pragma unroll
  for (int mf = 0; mf < 2; ++mf)
    #pragma unroll
    for (int j = 0; j < 4; ++j) {
      const int rg = aRow0 + wrBase + (mf << 4) + (hi << 2) + j;
      if (rg < ne) {
        const unsigned dst = (unsigned)ei[EE + e0 + rg];
        if (dst < NN) {
          float* ag = agg + ((size_t)dst << 6);
          #pragma unroll
          for (int nf = 0; nf < 4; ++nf)
            atomicAdd(ag + (nf << 4) + lo, msg[mf][nf][j]);
        }
      }
    }
}

// wt[n*K + k] = bf16(w[k*N + n])  (transpose + cast)
__global__ void convert_t(const float* __restrict__ w, bf16_t* __restrict__ wt,
                          int K, int N) {
  int idx = blockIdx.x * 256 + threadIdx.x;
  if (idx >= K * N) return;
  int n = idx / K, k = idx - n * K;
  wt[idx] = __float2bfloat16(w[(size_t)k * N + n]);
}

__global__ void fc1_kernel(const float* __restrict__ x, const float* __restrict__ w,
                           const float* __restrict__ b, float* __restrict__ h) {
  int idx = blockIdx.x * 256 + threadIdx.x;
  if (idx >= NN * 64) return;
  int n = idx >> 6, j = idx & 63;
  h[idx] = fmaf(x[n], w[j], b[j]);
}

__global__ void deg_kernel(const int* __restrict__ ei, float* __restrict__ deg) {
  int e = blockIdx.x * 256 + threadIdx.x;
  if (e < EE) {
    unsigned d = (unsigned)ei[EE + e];
    if (d < NN) atomicAdd(&deg[d], 1.0f);
  }
}

// e1[el][0:256] = relu(attr[e0+el] @ k1_w + k1_b), zeros for rows >= ne
__global__ void k1_kernel(const float* __restrict__ attr, const float* __restrict__ w,
                          const float* __restrict__ b, bf16_t* __restrict__ e1,
                          int e0, int ne) {
  const int el = blockIdx.x;
  const int j = threadIdx.x;
  __shared__ float a[6];
  if (el < ne && j < 6) a[j] = attr[(size_t)(e0 + el) * 6 + j];
  __syncthreads();
  float v = 0.0f;
  if (el < ne) {
    v = b[j];
    #pragma unroll
    for (int i = 0; i < 6; ++i) v = fmaf(a[i], w[i * 256 + j], v);
    v = fmaxf(v, 0.0f);
  }
  e1[(size_t)el * 256 + j] = __float2bfloat16(v);
}

// per-edge matvec from cached W (bf16): msg[o] = sum_i h[src][i]*W[el][i*64+o]
__global__ __launch_bounds__(256)
void msg_kernel(const float* __restrict__ h, const bf16_t* __restrict__ W,
                const int* __restrict__ ei, float* __restrict__ agg,
                int e0, int ne) {
  const int el = blockIdx.x * 4 + (threadIdx.x >> 6);
  if (el >= ne) return;
  const int e = e0 + el;
  const int lane = threadIdx.x & 63;
  const int g = lane >> 4, c = lane & 15;
  const unsigned src = (unsigned)ei[e], dst = (unsigned)ei[EE + e];
  if (src >= NN || dst >= NN) return;
  const float hv = h[src * 64 + lane];
  const unsigned short* We = (const unsigned short*)(W + (size_t)el * 4096);
  float a0 = 0, a1 = 0, a2 = 0, a3 = 0;
  #pragma unroll
  for (int i0 = 0; i0 < 64; i0 += 4) {
    const int i = i0 + g;
    const float hs = __shfl(hv, i);
    u16x4 wv = __builtin_nontemporal_load((const u16x4*)(We + i * 64 + c * 4));
    a0 = fmaf(hs, bf2f(wv[0]), a0);
    a1 = fmaf(hs, bf2f(wv[1]), a1);
    a2 = fmaf(hs, bf2f(wv[2]), a2);
    a3 = fmaf(hs, bf2f(wv[3]), a3);
  }
  a0 += __shfl_xor(a0, 16); a0 += __shfl_xor(a0, 32);
  a1 += __shfl_xor(a1, 16); a1 += __shfl_xor(a1, 32);
  a2 += __shfl_xor(a2, 16); a2 += __shfl_xor(a2, 32);
  a3 += __shfl_xor(a3, 16); a3 += __shfl_xor(a3, 32);
  if (g == 0) {
    float* ag = agg + (size_t)dst * 64 + c * 4;
    atomicAdd(ag + 0, a0);
    atomicAdd(ag + 1, a1);
    atomicAdd(ag + 2, a2);
    atomicAdd(ag + 3, a3);
  }
}

// h_new = relu(agg/deg + h @ root + gcn_b)
__global__ __launch_bounds__(256)
void update_kernel(const float* __restrict__ h, const float* __restrict__ agg,
                   const float* __restrict__ deg, const float* __restrict__ root,
                   const float* __restrict__ gb, float* __restrict__ hn) {
  const int n = blockIdx.x * 4 + (threadIdx.x >> 6);
  if (n >= NN) return;
  const int lane = threadIdx.x & 63;
  const float hv = h[n * 64 + lane];
  float acc = 0.0f;
  #pragma unroll
  for (int i = 0; i < 64; ++i)
    acc = fmaf(__shfl(hv, i), root[i * 64 + lane], acc);
  const float d = fmaxf(deg[n], 1.0f);
  const float v = agg[n * 64 + lane] / d + acc + gb[lane];
  hn[n * 64 + lane] = fmaxf(v, 0.0f);
}

__global__ __launch_bounds__(256)
void fc2_kernel(const float* __restrict__ h, const float* __restrict__ w,
                const float* __restrict__ b, float* __restrict__ out) {
  const int n = blockIdx.x * 4 + (threadIdx.x >> 6);
  if (n >= NN) return;
  const int lane = threadIdx.x & 63;
  float v = h[n * 64 + lane] * w[lane];
  #pragma unroll
  for (int off = 32; off > 0; off >>= 1) v += __shfl_xor(v, off);
  if (lane == 0) out[n] = v + b[0];
}

extern "C" void kernel_launch(void* const* d_in, const int* in_sizes, int n_in,
                              void* d_out, int out_size, void* d_ws, size_t ws_size,
                              hipStream_t stream) {
  const float* x     = (const float*)d_in[0];
  const int*   ei    = (const int*)d_in[1];
  const float* attr  = (const float*)d_in[2];
  const float* fc1_w = (const float*)d_in[3];
  const float* fc1_b = (const float*)d_in[4];
  const float* k1_w  = (const float*)d_in[5];
  const float* k1_b  = (const float*)d_in[6];
  const float* k2_w  = (const float*)d_in[7];
  const float* k2_b  = (const float*)d_in[8];
  const float* k3_w  = (const float*)d_in[9];
  const float* k3_b  = (const float*)d_in[10];
  const float* root  = (const float*)d_in[11];
  const float* gcn_b = (const float*)d_in[12];
  const float* fc2_w = (const float*)d_in[13];
  const float* fc2_b = (const float*)d_in[14];
  float* out = (float*)d_out;
  (void)in_sizes; (void)n_in; (void)out_size;

  char* ws = (char*)d_ws;
  size_t off = 0;
  auto take = [&](size_t bytes) -> char* {
    char* p = ws + off;
    off += (bytes + 255) & ~(size_t)255;
    return p;
  };
  // fixed small buffers (~12.2 MB)
  bf16_t* k2wt = (bf16_t*)take((size_t)512 * 256 * 2);
  bf16_t* k3wt = (bf16_t*)take((size_t)4096 * 512 * 2);
  float*  hA   = (float*)take((size_t)NN * 64 * 4);
  float*  hB   = (float*)take((size_t)NN * 64 * 4);
  float*  agg  = (float*)take((size_t)NN * 64 * 4);
  float*  deg  = (float*)take((size_t)NN * 4);

  // e2 for all edges (51.4 MB); remaining region = e1 (transient) then Wcache
  bf16_t* e2full = (bf16_t*)take((size_t)MPAD * 512 * 2);
  size_t rem = (ws_size > off + 1024) ? ws_size - off - 1024 : 0;
  int Nc = (int)((rem / 8192) / 128) * 128;  // cached edges, mult of 128
  if (Nc > 49920) Nc = 49920;  // keep Te >= 80 (never let Te < 0)
  if (Nc < 0) Nc = 0;
  size_t e1B = (size_t)MPAD * 256 * 2;  // 25.7 MB
  size_t regionB = (size_t)Nc * 8192;
  if (regionB < e1B) regionB = e1B;
  char* region = take(regionB);
  bf16_t* Wcache = (bf16_t*)region;
  bf16_t* e1 = (bf16_t*)region;  // dead after k2; overwritten by Wcache fill

  const int Te = EE - Nc;               // tail edges (fused per layer)
  const int Mt64 = (Te + 63) & ~63;     // padded to 64 (Nc + Mt64 <= MPAD)
  const int nmt = Mt64 >> 6;
  const int nFused = nmt * 4;           // fused blocks (s-major: fid = s*nmt + mt)
  int ratio = 1, MOD = 1, NcIn = 0;
  if (Nc > 0 && nFused > 0) {
    // msg blocks cover 8 edges each (2 per wave, interleaved)
    ratio = (((Nc + 7) >> 3) + nFused - 1) / nFused;
    if (ratio < 1) ratio = 1;
    MOD = ratio + 1;
    const long cap = (long)8 * ratio * nFused;
    NcIn = (Nc < cap) ? Nc : (int)cap;
  }
  const int NcOut = Nc - NcIn;

  // weight transposes + casts
  convert_t<<<(512 * 256 + 255) / 256, 256, 0, stream>>>(k2_w, k2wt, 256, 512);
  convert_t<<<(4096 * 512 + 255) / 256, 256, 0, stream>>>(k3_w, k3wt, 512, 4096);

  // h0 = x @ fc1_w + fc1_b
  fc1_kernel<<<(NN * 64 + 255) / 256, 256, 0, stream>>>(x, fc1_w, fc1_b, hA);

  // in-degree
  hipMemsetAsync(deg, 0, NN * 4, stream);
  deg_kernel<<<(EE + 255) / 256, 256, 0, stream>>>(ei, deg);

  // edge MLP front (full): k1 -> e1, k2 -> e2full
  k1_kernel<<<MPAD, 256, 0, stream>>>(attr, k1_w, k1_b, e1, 0, EE);
  gemm_bt<true><<<(MPAD >> 7) * 4, 256, 0, stream>>>(e1, k2wt, k2_b, e2full, 512, 256);

  // W cache fill (h-independent, once): proven 944-TF GEMM
  if (Nc > 0)
    gemm_bt<false><<<(Nc >> 7) * 32, 256, 0, stream>>>(e2full, k3wt, k3_b, Wcache, 4096, 512);

  float* hc = hA;
  float* hn = hB;
  for (int l = 0; l < 3; ++l) {
    hipMemsetAsync(agg, 0, (size_t)NN * 64 * 4, stream);
    if (Te > 0) {
      // merged dispatch: fused tail blocks (1/MOD) interleaved with cached-msg blocks
      layer_fused<<<nFused * MOD, 256, 0, stream>>>(e2full + (size_t)Nc * 512, k3wt, k3_b,
                                                    hc, Wcache, ei, agg, Nc, Te, nmt,
                                                    NcIn, MOD);
      if (NcOut > 0)
        msg_kernel<<<(NcOut + 3) / 4, 256, 0, stream>>>(hc, Wcache, ei, agg, NcIn, NcOut);
    } else if (Nc > 0) {
      msg_kernel<<<(Nc + 3) / 4, 256, 0, stream>>>(hc, Wcache, ei, agg, 0, Nc);
    }
    update_kernel<<<(NN + 3) / 4, 256, 0, stream>>>(hc, agg, deg, root, gcn_b, hn);
    float* tmp = hc; hc = hn; hn = tmp;
  }

  fc2_kernel<<<(NN + 3) / 4, 256, 0, stream>>>(hc, fc2_w, fc2_b, out);
}

// Round 17
// 534.563 us; speedup vs baseline: 1.5262x; 1.4095x over previous
//
#include <hip/hip_runtime.h>
#include <hip/hip_bf16.h>
#include <stdint.h>

#define NN 10000
#define EE 50000
#define MPAD 50176  // EE padded to multiple of 128

typedef __hip_bfloat16 bf16_t;
typedef __attribute__((ext_vector_type(8))) short bf16x8;
typedef __attribute__((ext_vector_type(4))) float f32x4;

__device__ __forceinline__ float bf2f(unsigned short u) {
  union { unsigned int i; float f; } v; v.i = ((unsigned int)u) << 16; return v.f;
}

__device__ __forceinline__ void async_load16(const void* g, void* lds) {
  __builtin_amdgcn_global_load_lds((const __attribute__((address_space(1))) uint32_t*)g,
                                   (__attribute__((address_space(3))) uint32_t*)lds,
                                   16, 0, 0);
}

#define MFMA16(a, b, c) __builtin_amdgcn_mfma_f32_16x16x32_bf16(a, b, c, 0, 0, 0)

// C[M][N] = act(A[M][K] @ Bt[N][K]^T + bias[N]); bf16 row-major, M,N mult 128, K mult 64.
// Proven r2 structure: 944 TF, MfmaUtil 42%, 0 bank conflicts. DO NOT TOUCH without A/B.
template <bool RELU>
__global__ __launch_bounds__(256, 2)
void gemm_bt(const bf16_t* __restrict__ A, const bf16_t* __restrict__ Bt,
             const float* __restrict__ bias, bf16_t* __restrict__ C,
             int N, int K) {
  __shared__ __align__(16) bf16_t As[128 * 64];
  __shared__ __align__(16) bf16_t Bs[128 * 64];

  const int t = threadIdx.x;
  const int lane = t & 63;
  const int wave = t >> 6;
  const int nt = N >> 7;
  const int bm = blockIdx.x / nt;
  const int bn = blockIdx.x % nt;
  const size_t aRowBase = (size_t)bm << 7;
  const size_t bRowBase = (size_t)bn << 7;

  const int wrBase = (wave >> 1) << 6;
  const int wcBase = (wave & 1) << 6;
  const int lo = lane & 15;
  const int hi = lane >> 4;

  f32x4 acc[4][4] = {};

  const int stg_r = t >> 3;
  const int stg_s = t & 7;
  char* AsB = (char*)As;
  char* BsB = (char*)Bs;

  const int nkt = K >> 6;
  for (int kt = 0; kt < nkt; ++kt) {
    __syncthreads();
    #pragma unroll
    for (int it = 0; it < 4; ++it) {
      const int r = (it << 5) + stg_r;
      const int ls = (stg_s ^ (r & 7)) << 3;
      async_load16(A + (aRowBase + r) * K + (kt << 6) + ls,
                   AsB + (it << 12) + (wave << 10));
      async_load16(Bt + (bRowBase + r) * K + (kt << 6) + ls,
                   BsB + (it << 12) + (wave << 10));
    }
    __syncthreads();
    #pragma unroll
    for (int ks = 0; ks < 2; ++ks) {
      bf16x8 af[4], bfr[4];
      #pragma unroll
      for (int m = 0; m < 4; ++m) {
        const int row = wrBase + (m << 4) + lo;
        const int ps = ((ks << 2) + hi) ^ (row & 7);
        af[m] = *(const bf16x8*)(AsB + (row << 7) + (ps << 4));
      }
      #pragma unroll
      for (int n = 0; n < 4; ++n) {
        const int row = wcBase + (n << 4) + lo;
        const int ps = ((ks << 2) + hi) ^ (row & 7);
        bfr[n] = *(const bf16x8*)(BsB + (row << 7) + (ps << 4));
      }
      #pragma unroll
      for (int m = 0; m < 4; ++m)
        #pragma unroll
        for (int n = 0; n < 4; ++n)
          acc[m][n] = MFMA16(af[m], bfr[n], acc[m][n]);
    }
  }

  #pragma unroll
  for (int m = 0; m < 4; ++m) {
    #pragma unroll
    for (int n = 0; n < 4; ++n) {
      const int col = (bn << 7) + wcBase + (n << 4) + lo;
      const float bv = bias[col];
      #pragma unroll
      for (int j = 0; j < 4; ++j) {
        const int row = (bm << 7) + wrBase + (m << 4) + (hi << 2) + j;
        float v = acc[m][n][j] + bv;
        if (RELU) v = fmaxf(v, 0.0f);
        C[(size_t)row * N + col] = __float2bfloat16(v);
      }
    }
  }
}

// k3 GEMM (no bias) with int8-quantizing epilogue.
// Wq[edge][i][byte: c*4+k] stores o = k*16+c (k=0..3, c=0..15) for i-block i = 2*bn + (wave&1).
// Sq[edge][i] = rowblock max/127 (f32). Per-(row,i) max over 64 cols via 4-step lo-lane butterfly.
__global__ __launch_bounds__(256, 2)
void gemm_q(const bf16_t* __restrict__ A, const bf16_t* __restrict__ Bt,
            char* __restrict__ Wq, float* __restrict__ Sq, int e0) {
  __shared__ __align__(16) bf16_t As[128 * 64];
  __shared__ __align__(16) bf16_t Bs[128 * 64];

  const int t = threadIdx.x;
  const int lane = t & 63;
  const int wave = t >> 6;
  const int bm = blockIdx.x >> 5;   // 32 col-tiles (N = 4096)
  const int bn = blockIdx.x & 31;
  const size_t aRowBase = (size_t)bm << 7;
  const size_t bRowBase = (size_t)bn << 7;

  const int wrBase = (wave >> 1) << 6;
  const int wcb = wave & 1;
  const int wcBase = wcb << 6;
  const int lo = lane & 15;
  const int hi = lane >> 4;

  f32x4 acc[4][4] = {};

  const int stg_r = t >> 3;
  const int stg_s = t & 7;
  char* AsB = (char*)As;
  char* BsB = (char*)Bs;

  for (int kt = 0; kt < 8; ++kt) {  // K = 512
    __syncthreads();
    #pragma unroll
    for (int it = 0; it < 4; ++it) {
      const int r = (it << 5) + stg_r;
      const int ls = (stg_s ^ (r & 7)) << 3;
      async_load16(A + (aRowBase + r) * 512 + (kt << 6) + ls,
                   AsB + (it << 12) + (wave << 10));
      async_load16(Bt + (bRowBase + r) * 512 + (kt << 6) + ls,
                   BsB + (it << 12) + (wave << 10));
    }
    __syncthreads();
    #pragma unroll
    for (int ks = 0; ks < 2; ++ks) {
      bf16x8 af[4], bfr[4];
      #pragma unroll
      for (int m = 0; m < 4; ++m) {
        const int row = wrBase + (m << 4) + lo;
        const int ps = ((ks << 2) + hi) ^ (row & 7);
        af[m] = *(const bf16x8*)(AsB + (row << 7) + (ps << 4));
      }
      #pragma unroll
      for (int n = 0; n < 4; ++n) {
        const int row = wcBase + (n << 4) + lo;
        const int ps = ((ks << 2) + hi) ^ (row & 7);
        bfr[n] = *(const bf16x8*)(BsB + (row << 7) + (ps << 4));
      }
      #pragma unroll
      for (int m = 0; m < 4; ++m)
        #pragma unroll
        for (int n = 0; n < 4; ++n)
          acc[m][n] = MFMA16(af[m], bfr[n], acc[m][n]);
    }
  }

  // quantizing epilogue (bias NOT included -- handled exactly via bterm in msg_q)
  const int ib = (bn << 1) + wcb;  // i block 0..63
  #pragma unroll
  for (int m = 0; m < 4; ++m) {
    #pragma unroll
    for (int j = 0; j < 4; ++j) {
      const int row = (bm << 7) + wrBase + (m << 4) + (hi << 2) + j;
      float mx = 0.0f;
      #pragma unroll
      for (int n = 0; n < 4; ++n) mx = fmaxf(mx, fabsf(acc[m][n][j]));
      mx = fmaxf(mx, __shfl_xor(mx, 1));
      mx = fmaxf(mx, __shfl_xor(mx, 2));
      mx = fmaxf(mx, __shfl_xor(mx, 4));
      mx = fmaxf(mx, __shfl_xor(mx, 8));
      const float inv = (mx > 0.0f) ? (127.0f / mx) : 0.0f;
      char4 qb;
      qb.x = (signed char)(int)rintf(acc[m][0][j] * inv);
      qb.y = (signed char)(int)rintf(acc[m][1][j] * inv);
      qb.z = (signed char)(int)rintf(acc[m][2][j] * inv);
      qb.w = (signed char)(int)rintf(acc[m][3][j] * inv);
      *(char4*)(Wq + ((size_t)(e0 + row) << 12) + (ib << 6) + (lo << 2)) = qb;
      if (lo == 0) Sq[((size_t)(e0 + row) << 6) + ib] = mx * (1.0f / 127.0f);
    }
  }
}

// per-edge matvec from int8 W-cache: msg[o] = sum_i h[src][i]*s[i]*q[i][o] + bterm[src][o].
// Lane (g = lane>>4, c = lane&15) handles i = i0+g, o = k*16+c (k=0..3) -- matches gemm_q layout.
// 8 edges/block, 2 per wave interleaved (MLP).
__global__ __launch_bounds__(256)
void msg_q(const float* __restrict__ h, const char* __restrict__ Wq,
           const float* __restrict__ Sq, const float* __restrict__ bterm,
           const int* __restrict__ ei, float* __restrict__ agg, int ne) {
  const int t = threadIdx.x, lane = t & 63;
  const int base = (blockIdx.x << 3) + (t >> 6);
  const int el0 = base, el1 = base + 4;
  bool v0 = el0 < ne, v1 = el1 < ne;
  unsigned s0 = 0, d0 = 0, s1 = 0, d1 = 0;
  if (v0) { s0 = (unsigned)ei[el0]; d0 = (unsigned)ei[EE + el0];
            if (s0 >= NN || d0 >= NN) v0 = false; }
  if (v1) { s1 = (unsigned)ei[el1]; d1 = (unsigned)ei[EE + el1];
            if (s1 >= NN || d1 >= NN) v1 = false; }
  const int g = lane >> 4, c = lane & 15;
  const float hv0 = v0 ? h[s0 * 64 + lane] : 0.0f;
  const float hv1 = v1 ? h[s1 * 64 + lane] : 0.0f;
  const char* W0 = Wq + ((size_t)(v0 ? el0 : 0) << 12);
  const char* W1 = Wq + ((size_t)(v1 ? el1 : 0) << 12);
  const float* S0 = Sq + ((size_t)(v0 ? el0 : 0) << 6);
  const float* S1 = Sq + ((size_t)(v1 ? el1 : 0) << 6);
  float a0[4] = {}, a1[4] = {};
  #pragma unroll
  for (int i0 = 0; i0 < 64; i0 += 4) {
    const int i = i0 + g;
    const float hs0 = __shfl(hv0, i) * S0[i];
    const float hs1 = __shfl(hv1, i) * S1[i];
    const char4 q0 = *(const char4*)(W0 + (i << 6) + (c << 2));
    const char4 q1 = *(const char4*)(W1 + (i << 6) + (c << 2));
    a0[0] = fmaf(hs0, (float)q0.x, a0[0]);
    a0[1] = fmaf(hs0, (float)q0.y, a0[1]);
    a0[2] = fmaf(hs0, (float)q0.z, a0[2]);
    a0[3] = fmaf(hs0, (float)q0.w, a0[3]);
    a1[0] = fmaf(hs1, (float)q1.x, a1[0]);
    a1[1] = fmaf(hs1, (float)q1.y, a1[1]);
    a1[2] = fmaf(hs1, (float)q1.z, a1[2]);
    a1[3] = fmaf(hs1, (float)q1.w, a1[3]);
  }
  #pragma unroll
  for (int k = 0; k < 4; ++k) {
    a0[k] += __shfl_xor(a0[k], 16); a0[k] += __shfl_xor(a0[k], 32);
    a1[k] += __shfl_xor(a1[k], 16); a1[k] += __shfl_xor(a1[k], 32);
  }
  if (g == 0) {
    if (v0) {
      #pragma unroll
      for (int k = 0; k < 4; ++k) {
        const int o = (k << 4) + c;
        atomicAdd(agg + ((size_t)d0 << 6) + o, a0[k] + bterm[((size_t)s0 << 6) + o]);
      }
    }
    if (v1) {
      #pragma unroll
      for (int k = 0; k < 4; ++k) {
        const int o = (k << 4) + c;
        atomicAdd(agg + ((size_t)d1 << 6) + o, a1[k] + bterm[((size_t)s1 << 6) + o]);
      }
    }
  }
}

// bterm[n][o] = sum_i h[n][i] * b3[i*64+o]  (exact fp32 bias path)
__global__ __launch_bounds__(256)
void bterm_kernel(const float* __restrict__ h, const float* __restrict__ b3,
                  float* __restrict__ bt) {
  const int n = blockIdx.x * 4 + (threadIdx.x >> 6);
  if (n >= NN) return;
  const int lane = threadIdx.x & 63;
  const float hv = h[n * 64 + lane];
  float acc = 0.0f;
  #pragma unroll
  for (int i = 0; i < 64; ++i)
    acc = fmaf(__shfl(hv, i), b3[i * 64 + lane], acc);
  bt[(size_t)n * 64 + lane] = acc;
}

// wt[n*K + k] = bf16(w[k*N + n])  (transpose + cast)
__global__ void convert_t(const float* __restrict__ w, bf16_t* __restrict__ wt,
                          int K, int N) {
  int idx = blockIdx.x * 256 + threadIdx.x;
  if (idx >= K * N) return;
  int n = idx / K, k = idx - n * K;
  wt[idx] = __float2bfloat16(w[(size_t)k * N + n]);
}

__global__ void fc1_kernel(const float* __restrict__ x, const float* __restrict__ w,
                           const float* __restrict__ b, float* __restrict__ h) {
  int idx = blockIdx.x * 256 + threadIdx.x;
  if (idx >= NN * 64) return;
  int n = idx >> 6, j = idx & 63;
  h[idx] = fmaf(x[n], w[j], b[j]);
}

__global__ void deg_kernel(const int* __restrict__ ei, float* __restrict__ deg) {
  int e = blockIdx.x * 256 + threadIdx.x;
  if (e < EE) {
    unsigned d = (unsigned)ei[EE + e];
    if (d < NN) atomicAdd(&deg[d], 1.0f);
  }
}

// e1[el][0:256] = relu(attr[e0+el] @ k1_w + k1_b), zeros for rows >= ne
__global__ void k1_kernel(const float* __restrict__ attr, const float* __restrict__ w,
                          const float* __restrict__ b, bf16_t* __restrict__ e1,
                          int e0, int ne) {
  const int el = blockIdx.x;
  const int j = threadIdx.x;
  __shared__ float a[6];
  if (el < ne && j < 6) a[j] = attr[(size_t)(e0 + el) * 6 + j];
  __syncthreads();
  float v = 0.0f;
  if (el < ne) {
    v = b[j];
    #pragma unroll
    for (int i = 0; i < 6; ++i) v = fmaf(a[i], w[i * 256 + j], v);
    v = fmaxf(v, 0.0f);
  }
  e1[(size_t)el * 256 + j] = __float2bfloat16(v);
}

// h_new = relu(agg/deg + h @ root + gcn_b)
__global__ __launch_bounds__(256)
void update_kernel(const float* __restrict__ h, const float* __restrict__ agg,
                   const float* __restrict__ deg, const float* __restrict__ root,
                   const float* __restrict__ gb, float* __restrict__ hn) {
  const int n = blockIdx.x * 4 + (threadIdx.x >> 6);
  if (n >= NN) return;
  const int lane = threadIdx.x & 63;
  const float hv = h[n * 64 + lane];
  float acc = 0.0f;
  #pragma unroll
  for (int i = 0; i < 64; ++i)
    acc = fmaf(__shfl(hv, i), root[i * 64 + lane], acc);
  const float d = fmaxf(deg[n], 1.0f);
  const float v = agg[n * 64 + lane] / d + acc + gb[lane];
  hn[n * 64 + lane] = fmaxf(v, 0.0f);
}

__global__ __launch_bounds__(256)
void fc2_kernel(const float* __restrict__ h, const float* __restrict__ w,
                const float* __restrict__ b, float* __restrict__ out) {
  const int n = blockIdx.x * 4 + (threadIdx.x >> 6);
  if (n >= NN) return;
  const int lane = threadIdx.x & 63;
  float v = h[n * 64 + lane] * w[lane];
  #pragma unroll
  for (int off = 32; off > 0; off >>= 1) v += __shfl_xor(v, off);
  if (lane == 0) out[n] = v + b[0];
}

extern "C" void kernel_launch(void* const* d_in, const int* in_sizes, int n_in,
                              void* d_out, int out_size, void* d_ws, size_t ws_size,
                              hipStream_t stream) {
  const float* x     = (const float*)d_in[0];
  const int*   ei    = (const int*)d_in[1];
  const float* attr  = (const float*)d_in[2];
  const float* fc1_w = (const float*)d_in[3];
  const float* fc1_b = (const float*)d_in[4];
  const float* k1_w  = (const float*)d_in[5];
  const float* k1_b  = (const float*)d_in[6];
  const float* k2_w  = (const float*)d_in[7];
  const float* k2_b  = (const float*)d_in[8];
  const float* k3_w  = (const float*)d_in[9];
  const float* k3_b  = (const float*)d_in[10];
  const float* root  = (const float*)d_in[11];
  const float* gcn_b = (const float*)d_in[12];
  const float* fc2_w = (const float*)d_in[13];
  const float* fc2_b = (const float*)d_in[14];
  float* out = (float*)d_out;
  (void)in_sizes; (void)n_in; (void)out_size; (void)ws_size;

  char* ws = (char*)d_ws;
  size_t off = 0;
  auto take = [&](size_t bytes) -> char* {
    char* p = ws + off;
    off += (bytes + 255) & ~(size_t)255;
    return p;
  };
  // fixed buffers (~14.8 MB)
  bf16_t* k2wt  = (bf16_t*)take((size_t)512 * 256 * 2);
  bf16_t* k3wt  = (bf16_t*)take((size_t)4096 * 512 * 2);
  float*  hA    = (float*)take((size_t)NN * 64 * 4);
  float*  hB    = (float*)take((size_t)NN * 64 * 4);
  float*  agg   = (float*)take((size_t)NN * 64 * 4);
  float*  deg   = (float*)take((size_t)NN * 4);
  float*  bterm = (float*)take((size_t)NN * 64 * 4);
  // chunked fill scratch (3 chunks of 16768 edges): e1c 8.6MB + e2c 17.2MB
  const int Cc = 16768;
  bf16_t* e1c = (bf16_t*)take((size_t)Cc * 256 * 2);
  bf16_t* e2c = (bf16_t*)take((size_t)Cc * 512 * 2);
  // int8 W cache: Wq 205.5MB + Sq 12.85MB  (total ~259MB <= 256MiB ws)
  float* Sq = (float*)take((size_t)MPAD * 64 * 4);
  char*  Wq = take((size_t)MPAD * 4096);

  // weight transposes + casts
  convert_t<<<(512 * 256 + 255) / 256, 256, 0, stream>>>(k2_w, k2wt, 256, 512);
  convert_t<<<(4096 * 512 + 255) / 256, 256, 0, stream>>>(k3_w, k3wt, 512, 4096);

  // h0 = x @ fc1_w + fc1_b
  fc1_kernel<<<(NN * 64 + 255) / 256, 256, 0, stream>>>(x, fc1_w, fc1_b, hA);

  // in-degree
  hipMemsetAsync(deg, 0, NN * 4, stream);
  deg_kernel<<<(EE + 255) / 256, 256, 0, stream>>>(ei, deg);

  // fill int8 W-cache in 3 chunks: k1 -> e1c, k2 -> e2c, gemm_q -> Wq+Sq
  for (int e0 = 0; e0 < EE; e0 += Cc) {
    int ne = EE - e0; if (ne > Cc) ne = Cc;
    const int np = (ne + 127) & ~127;
    k1_kernel<<<np, 256, 0, stream>>>(attr, k1_w, k1_b, e1c, e0, ne);
    gemm_bt<true><<<(np >> 7) * 4, 256, 0, stream>>>(e1c, k2wt, k2_b, e2c, 512, 256);
    gemm_q<<<(np >> 7) * 32, 256, 0, stream>>>(e2c, k3wt, Wq, Sq, e0);
  }

  float* hc = hA;
  float* hn = hB;
  for (int l = 0; l < 3; ++l) {
    hipMemsetAsync(agg, 0, (size_t)NN * 64 * 4, stream);
    bterm_kernel<<<(NN + 3) / 4, 256, 0, stream>>>(hc, k3_b, bterm);
    msg_q<<<(EE + 7) / 8, 256, 0, stream>>>(hc, Wq, Sq, bterm, ei, agg, EE);
    update_kernel<<<(NN + 3) / 4, 256, 0, stream>>>(hc, agg, deg, root, gcn_b, hn);
    float* tmp = hc; hc = hn; hn = tmp;
  }

  fc2_kernel<<<(NN + 3) / 4, 256, 0, stream>>>(hc, fc2_w, fc2_b, out);
}